// Round 6
// baseline (394.531 us; speedup 1.0000x reference)
//
#include <hip/hip_runtime.h>
#include <stdint.h>

#define SEQ    2048
#define NB     2
#define DMODEL 1024
#define NHEAD  16
#define HDIM   64
#define FFDIM  4096
#define WIN    128
#define MTOK   (NB*SEQ)   // 4096 tokens

typedef short short8 __attribute__((ext_vector_type(8)));  // 8 bf16 (4 VGPRs)
typedef float f32x4  __attribute__((ext_vector_type(4)));

__device__ __forceinline__ float bf2f(uint16_t h){ return __uint_as_float(((uint32_t)h) << 16); }
__device__ __forceinline__ uint16_t f2bf(float f){           // RNE f32->bf16
  uint32_t u = __float_as_uint(f);
  u += 0x7fffu + ((u >> 16) & 1u);
  return (uint16_t)(u >> 16);
}
__device__ __forceinline__ int sw4(int r){ return (r ^ (r >> 2)) & 3; }

__device__ __forceinline__ void gl_lds16(const void* g, void* l) {
  __builtin_amdgcn_global_load_lds((const __attribute__((address_space(1))) void*)g,
                                   (__attribute__((address_space(3))) void*)l, 16, 0, 0);
}

// ---------- fused fp32->bf16 weight convert (wqkv|wout|wff1|wff2) ----------
__global__ __launch_bounds__(256) void cvt4_kernel(
    const float* __restrict__ s0, const float* __restrict__ s1,
    const float* __restrict__ s2, const float* __restrict__ s3,
    uint16_t* __restrict__ d0, uint16_t* __restrict__ d1,
    uint16_t* __restrict__ d2, uint16_t* __restrict__ d3)
{
  size_t i = (size_t)blockIdx.x * 256 + threadIdx.x;   // float4 index; 3M total
  const float* s; uint16_t* d; size_t off;
  if      (i <  768*1024) { s = s0; d = d0; off = i; }
  else if (i < 1024*1024) { s = s1; d = d1; off = i -  768*1024; }
  else if (i < 2048*1024) { s = s2; d = d2; off = i - 1024*1024; }
  else                    { s = s3; d = d3; off = i - 2048*1024; }
  const float4 v = ((const float4*)s)[off];
  uint2 o;
  o.x = (uint32_t)f2bf(v.x) | ((uint32_t)f2bf(v.y) << 16);
  o.y = (uint32_t)f2bf(v.z) | ((uint32_t)f2bf(v.w) << 16);
  ((uint2*)d)[off] = o;
}

// -------- LayerNorm: fp32 in -> bf16 out; one row (1024) per block ---------
__global__ __launch_bounds__(256) void ln_kernel(const float* __restrict__ x,
                                                 const float* __restrict__ g,
                                                 const float* __restrict__ b,
                                                 uint16_t* __restrict__ y)
{
  const int row = blockIdx.x;
  const int t = threadIdx.x;
  const float4 v = ((const float4*)(x + (size_t)row * DMODEL))[t];
  float s1 = v.x + v.y + v.z + v.w;
  float s2 = v.x*v.x + v.y*v.y + v.z*v.z + v.w*v.w;
  #pragma unroll
  for (int off = 32; off; off >>= 1) { s1 += __shfl_xor(s1, off, 64); s2 += __shfl_xor(s2, off, 64); }
  __shared__ float red[8];
  const int w = t >> 6;
  if ((t & 63) == 0) { red[w] = s1; red[4+w] = s2; }
  __syncthreads();
  s1 = red[0]+red[1]+red[2]+red[3];
  s2 = red[4]+red[5]+red[6]+red[7];
  const float mu = s1 * (1.0f/DMODEL);
  const float var = s2 * (1.0f/DMODEL) - mu*mu;
  const float rs = rsqrtf(var + 1e-5f);
  const float4 gv = ((const float4*)g)[t];
  const float4 bv = ((const float4*)b)[t];
  uint2 o;
  o.x = (uint32_t)f2bf((v.x-mu)*rs*gv.x + bv.x) | ((uint32_t)f2bf((v.y-mu)*rs*gv.y + bv.y) << 16);
  o.y = (uint32_t)f2bf((v.z-mu)*rs*gv.z + bv.z) | ((uint32_t)f2bf((v.w-mu)*rs*gv.w + bv.w) << 16);
  ((uint2*)(y + (size_t)row * DMODEL))[t] = o;
}

// ---------- GEMM 128x128: C[M,N] = A[M,K] @ Bm[N,K]^T (+epilogue) ----------
// EPI: 0 none (bf16 C), 2 +bias then exact GELU (bf16 C)
template<int EPI>
__global__ __launch_bounds__(256) void gemm_bt(
    const uint16_t* __restrict__ A, const uint16_t* __restrict__ Bm,
    const float* __restrict__ bias, uint16_t* __restrict__ C,
    int M, int N, int K)
{
  __shared__ __align__(16) uint16_t As[128*32];
  __shared__ __align__(16) uint16_t Bs[128*32];
  const int t = threadIdx.x;
  const int l = t & 63;
  const int w = t >> 6;
  const int row0 = blockIdx.y * 128;
  const int col0 = blockIdx.x * 128;
  const int wm = (w >> 1) * 64, wn = (w & 1) * 64;

  f32x4 acc[4][4];
  #pragma unroll
  for (int i = 0; i < 4; ++i)
    #pragma unroll
    for (int j = 0; j < 4; ++j)
      #pragma unroll
      for (int e = 0; e < 4; ++e) acc[i][j][e] = 0.0f;

  const int sr = t >> 2, ss = t & 3;
  const int sg = ss ^ sw4(sr);
  const uint16_t* aG = A  + (size_t)(row0 + sr) * K + sg * 8;
  const uint16_t* bG = Bm + (size_t)(col0 + sr) * K + sg * 8;
  char* aL = (char*)As + t * 16;
  char* bL = (char*)Bs + t * 16;
  const int mrow = l & 15;
  const int slot = (l >> 4) ^ sw4(mrow);

  for (int k0 = 0; k0 < K; k0 += 32) {
    gl_lds16(aG + k0,                   aL);
    gl_lds16(aG + k0 + (size_t)64 * K,  aL + 4096);
    gl_lds16(bG + k0,                   bL);
    gl_lds16(bG + k0 + (size_t)64 * K,  bL + 4096);
    __syncthreads();
    short8 af[4], bfr[4];
    #pragma unroll
    for (int mi = 0; mi < 4; ++mi)
      af[mi] = *(const short8*)((const char*)As + (wm + mi*16 + mrow) * 64 + slot * 16);
    #pragma unroll
    for (int ni = 0; ni < 4; ++ni)
      bfr[ni] = *(const short8*)((const char*)Bs + (wn + ni*16 + mrow) * 64 + slot * 16);
    #pragma unroll
    for (int mi = 0; mi < 4; ++mi)
      #pragma unroll
      for (int ni = 0; ni < 4; ++ni)
        acc[mi][ni] = __builtin_amdgcn_mfma_f32_16x16x32_bf16(af[mi], bfr[ni], acc[mi][ni], 0, 0, 0);
    __syncthreads();
  }

  const int crow = (l >> 4) * 4;   // C/D: col = lane&15, row = (lane>>4)*4 + reg
  float bv[4];
  #pragma unroll
  for (int ni = 0; ni < 4; ++ni)
    bv[ni] = (EPI != 0) ? bias[col0 + wn + ni*16 + mrow] : 0.0f;
  #pragma unroll
  for (int mi = 0; mi < 4; ++mi) {
    #pragma unroll
    for (int r = 0; r < 4; ++r) {
      const int row = row0 + wm + mi*16 + crow + r;
      #pragma unroll
      for (int ni = 0; ni < 4; ++ni) {
        const int col = col0 + wn + ni*16 + mrow;
        float v = acc[mi][ni][r] + bv[ni];
        if (EPI == 2) v = 0.5f * v * (1.0f + erff(v * 0.70710678118654752f));
        C[(size_t)row * N + col] = f2bf(v);
      }
    }
  }
}

// ------- split-K GEMM, 128x64 tile: fp32 partial, no bias (out-proj) -------
// blockIdx.z selects K-slice of length KS; partial z written to Pz.
__global__ __launch_bounds__(256) void gemm_sk64(
    const uint16_t* __restrict__ A, const uint16_t* __restrict__ Bm,
    float* __restrict__ P0, float* __restrict__ P1,
    int M, int N, int K, int KS)
{
  __shared__ __align__(16) uint16_t As[128*32];
  __shared__ __align__(16) uint16_t Bs[64*32];
  const int t = threadIdx.x;
  const int l = t & 63;
  const int w = t >> 6;
  const int row0 = blockIdx.y * 128;
  const int col0 = blockIdx.x * 64;
  const int kbase = blockIdx.z * KS;
  float* P = blockIdx.z ? P1 : P0;
  const int wm = (w >> 1) * 64, wn = (w & 1) * 32;

  f32x4 acc[4][2];
  #pragma unroll
  for (int i = 0; i < 4; ++i)
    #pragma unroll
    for (int j = 0; j < 2; ++j)
      #pragma unroll
      for (int e = 0; e < 4; ++e) acc[i][j][e] = 0.0f;

  const int sr = t >> 2, ss = t & 3;
  const int sg = ss ^ sw4(sr);
  const uint16_t* aG = A  + (size_t)(row0 + sr) * K + kbase + sg * 8;
  const uint16_t* bG = Bm + (size_t)(col0 + sr) * K + kbase + sg * 8;
  char* aL = (char*)As + t * 16;
  char* bL = (char*)Bs + t * 16;
  const int mrow = l & 15;
  const int slot = (l >> 4) ^ sw4(mrow);

  for (int k0 = 0; k0 < KS; k0 += 32) {
    gl_lds16(aG + k0,                   aL);
    gl_lds16(aG + k0 + (size_t)64 * K,  aL + 4096);
    gl_lds16(bG + k0,                   bL);
    __syncthreads();
    short8 af[4], bfr[2];
    #pragma unroll
    for (int mi = 0; mi < 4; ++mi)
      af[mi] = *(const short8*)((const char*)As + (wm + mi*16 + mrow) * 64 + slot * 16);
    #pragma unroll
    for (int ni = 0; ni < 2; ++ni)
      bfr[ni] = *(const short8*)((const char*)Bs + (wn + ni*16 + mrow) * 64 + slot * 16);
    #pragma unroll
    for (int mi = 0; mi < 4; ++mi)
      #pragma unroll
      for (int ni = 0; ni < 2; ++ni)
        acc[mi][ni] = __builtin_amdgcn_mfma_f32_16x16x32_bf16(af[mi], bfr[ni], acc[mi][ni], 0, 0, 0);
    __syncthreads();
  }

  const int crow = (l >> 4) * 4;
  #pragma unroll
  for (int mi = 0; mi < 4; ++mi)
    #pragma unroll
    for (int r = 0; r < 4; ++r) {
      const int row = row0 + wm + mi*16 + crow + r;
      #pragma unroll
      for (int ni = 0; ni < 2; ++ni)
        P[(size_t)row * N + col0 + wn + ni*16 + mrow] = acc[mi][ni][r];
    }
}

// ------- split-K GEMM, 128x128 tile: bf16 partial, no bias (FF2) -----------
__global__ __launch_bounds__(256) void gemm_sk128(
    const uint16_t* __restrict__ A, const uint16_t* __restrict__ Bm,
    uint16_t* __restrict__ P0, uint16_t* __restrict__ P1,
    uint16_t* __restrict__ P2, uint16_t* __restrict__ P3,
    int M, int N, int K, int KS)
{
  __shared__ __align__(16) uint16_t As[128*32];
  __shared__ __align__(16) uint16_t Bs[128*32];
  const int t = threadIdx.x;
  const int l = t & 63;
  const int w = t >> 6;
  const int row0 = blockIdx.y * 128;
  const int col0 = blockIdx.x * 128;
  const int z = blockIdx.z;
  const int kbase = z * KS;
  uint16_t* P = (z < 2) ? (z ? P1 : P0) : (z == 2 ? P2 : P3);
  const int wm = (w >> 1) * 64, wn = (w & 1) * 64;

  f32x4 acc[4][4];
  #pragma unroll
  for (int i = 0; i < 4; ++i)
    #pragma unroll
    for (int j = 0; j < 4; ++j)
      #pragma unroll
      for (int e = 0; e < 4; ++e) acc[i][j][e] = 0.0f;

  const int sr = t >> 2, ss = t & 3;
  const int sg = ss ^ sw4(sr);
  const uint16_t* aG = A  + (size_t)(row0 + sr) * K + kbase + sg * 8;
  const uint16_t* bG = Bm + (size_t)(col0 + sr) * K + kbase + sg * 8;
  char* aL = (char*)As + t * 16;
  char* bL = (char*)Bs + t * 16;
  const int mrow = l & 15;
  const int slot = (l >> 4) ^ sw4(mrow);

  for (int k0 = 0; k0 < KS; k0 += 32) {
    gl_lds16(aG + k0,                   aL);
    gl_lds16(aG + k0 + (size_t)64 * K,  aL + 4096);
    gl_lds16(bG + k0,                   bL);
    gl_lds16(bG + k0 + (size_t)64 * K,  bL + 4096);
    __syncthreads();
    short8 af[4], bfr[4];
    #pragma unroll
    for (int mi = 0; mi < 4; ++mi)
      af[mi] = *(const short8*)((const char*)As + (wm + mi*16 + mrow) * 64 + slot * 16);
    #pragma unroll
    for (int ni = 0; ni < 4; ++ni)
      bfr[ni] = *(const short8*)((const char*)Bs + (wn + ni*16 + mrow) * 64 + slot * 16);
    #pragma unroll
    for (int mi = 0; mi < 4; ++mi)
      #pragma unroll
      for (int ni = 0; ni < 4; ++ni)
        acc[mi][ni] = __builtin_amdgcn_mfma_f32_16x16x32_bf16(af[mi], bfr[ni], acc[mi][ni], 0, 0, 0);
    __syncthreads();
  }

  const int crow = (l >> 4) * 4;
  #pragma unroll
  for (int mi = 0; mi < 4; ++mi)
    #pragma unroll
    for (int r = 0; r < 4; ++r) {
      const int row = row0 + wm + mi*16 + crow + r;
      #pragma unroll
      for (int ni = 0; ni < 4; ++ni)
        P[(size_t)row * N + col0 + wn + ni*16 + mrow] = f2bf(acc[mi][ni][r]);
    }
}

// ---- combine out-proj partials + bias + residual, then LN2, in one pass ---
// x2 = p0+p1+bout+x  -> write X2f (fp32) and H2 = LN(x2) (bf16)
__global__ __launch_bounds__(256) void combine_ln2_kernel(
    const float* __restrict__ p0, const float* __restrict__ p1,
    const float* __restrict__ x,  const float* __restrict__ bout,
    const float* __restrict__ g,  const float* __restrict__ b,
    float* __restrict__ X2f, uint16_t* __restrict__ H2)
{
  const int row = blockIdx.x;
  const int t = threadIdx.x;
  const size_t off = (size_t)row * (DMODEL/4) + t;
  const float4 a0 = ((const float4*)p0)[off];
  const float4 a1 = ((const float4*)p1)[off];
  const float4 xv = ((const float4*)x)[off];
  const float4 bo = ((const float4*)bout)[t];
  float4 v;
  v.x = a0.x + a1.x + xv.x + bo.x;
  v.y = a0.y + a1.y + xv.y + bo.y;
  v.z = a0.z + a1.z + xv.z + bo.z;
  v.w = a0.w + a1.w + xv.w + bo.w;
  ((float4*)X2f)[off] = v;
  float s1 = v.x + v.y + v.z + v.w;
  float s2 = v.x*v.x + v.y*v.y + v.z*v.z + v.w*v.w;
  #pragma unroll
  for (int o = 32; o; o >>= 1) { s1 += __shfl_xor(s1, o, 64); s2 += __shfl_xor(s2, o, 64); }
  __shared__ float red[8];
  const int w = t >> 6;
  if ((t & 63) == 0) { red[w] = s1; red[4+w] = s2; }
  __syncthreads();
  s1 = red[0]+red[1]+red[2]+red[3];
  s2 = red[4]+red[5]+red[6]+red[7];
  const float mu = s1 * (1.0f/DMODEL);
  const float var = s2 * (1.0f/DMODEL) - mu*mu;
  const float rs = rsqrtf(var + 1e-5f);
  const float4 gv = ((const float4*)g)[t];
  const float4 bv = ((const float4*)b)[t];
  uint2 o;
  o.x = (uint32_t)f2bf((v.x-mu)*rs*gv.x + bv.x) | ((uint32_t)f2bf((v.y-mu)*rs*gv.y + bv.y) << 16);
  o.y = (uint32_t)f2bf((v.z-mu)*rs*gv.z + bv.z) | ((uint32_t)f2bf((v.w-mu)*rs*gv.w + bv.w) << 16);
  ((uint2*)(H2 + (size_t)row * DMODEL))[t] = o;
}

// ---------- combine FF2 bf16 partials + bias + residual -> fp32 out --------
__global__ __launch_bounds__(256) void combine_ff2_kernel(
    const uint16_t* __restrict__ p0, const uint16_t* __restrict__ p1,
    const uint16_t* __restrict__ p2, const uint16_t* __restrict__ p3,
    const float* __restrict__ bff2, const float* __restrict__ X2f,
    float* __restrict__ out)
{
  const int row = blockIdx.x;
  const int t = threadIdx.x;
  const size_t eoff = (size_t)row * DMODEL + t * 4;
  const uint2 u0 = *(const uint2*)(p0 + eoff);
  const uint2 u1 = *(const uint2*)(p1 + eoff);
  const uint2 u2 = *(const uint2*)(p2 + eoff);
  const uint2 u3 = *(const uint2*)(p3 + eoff);
  const float4 xv = ((const float4*)X2f)[(size_t)row * (DMODEL/4) + t];
  const float4 bo = ((const float4*)bff2)[t];
  float4 v;
  v.x = bf2f((uint16_t)(u0.x & 0xffff)) + bf2f((uint16_t)(u1.x & 0xffff))
      + bf2f((uint16_t)(u2.x & 0xffff)) + bf2f((uint16_t)(u3.x & 0xffff)) + bo.x + xv.x;
  v.y = bf2f((uint16_t)(u0.x >> 16)) + bf2f((uint16_t)(u1.x >> 16))
      + bf2f((uint16_t)(u2.x >> 16)) + bf2f((uint16_t)(u3.x >> 16)) + bo.y + xv.y;
  v.z = bf2f((uint16_t)(u0.y & 0xffff)) + bf2f((uint16_t)(u1.y & 0xffff))
      + bf2f((uint16_t)(u2.y & 0xffff)) + bf2f((uint16_t)(u3.y & 0xffff)) + bo.z + xv.z;
  v.w = bf2f((uint16_t)(u0.y >> 16)) + bf2f((uint16_t)(u1.y >> 16))
      + bf2f((uint16_t)(u2.y >> 16)) + bf2f((uint16_t)(u3.y >> 16)) + bo.w + xv.w;
  ((float4*)out)[(size_t)row * (DMODEL/4) + t] = v;
}

// --------------------- local-window attention (MFMA) -----------------------
#define TQ    32
#define NKT   18
#define NKP   (NKT*16)   // 288 key slots
#define KSTR  72         // Qs/KV row stride (bf16)
#define PSTR  296        // Ps/Vt row stride (bf16)

__global__ __launch_bounds__(256) void attn_kernel(const uint16_t* __restrict__ qkv,
                                                   uint16_t* __restrict__ out)
{
  __shared__ uint16_t Qs[TQ * KSTR];
  __shared__ uint16_t Ps[TQ * PSTR];
  __shared__ uint16_t KV[NKP * KSTR];
  const int t = threadIdx.x, l = t & 63, w = t >> 6;
  const int b = blockIdx.z, hh = blockIdx.y, q0 = blockIdx.x * TQ;
  const int k0 = (q0 - WIN > 0) ? (q0 - WIN) : 0;
  const int kend_ = q0 + TQ + WIN;
  const int kend = (kend_ < SEQ) ? kend_ : SEQ;
  const int nk = kend - k0;

  {
    const int r = t >> 3, gg = t & 7;
    const uint4 qv = *(const uint4*)(qkv + (size_t)(b*SEQ + q0 + r) * 3072 + hh*64 + gg*8);
    *(uint4*)((char*)Qs + r*(KSTR*2) + gg*16) = qv;
    for (int j = r; j < NKP; j += 32) {
      uint4 kv; kv.x = 0; kv.y = 0; kv.z = 0; kv.w = 0;
      if (j < nk)
        kv = *(const uint4*)(qkv + (size_t)(b*SEQ + k0 + j) * 3072 + 1024 + hh*64 + gg*8);
      *(uint4*)((char*)KV + j*(KSTR*2) + gg*16) = kv;
    }
  }
  __syncthreads();

  if (w < 2) {
    const int rb = w * 16;
    const int mrow = l & 15, q4 = l >> 4;
    const short8 aq0 = *(const short8*)((const char*)Qs + (rb + mrow)*(KSTR*2) + q4*16);
    const short8 aq1 = *(const short8*)((const char*)Qs + (rb + mrow)*(KSTR*2) + 64 + q4*16);
    f32x4 cacc[NKT];
    #pragma unroll
    for (int ct = 0; ct < NKT; ++ct) {
      f32x4 c; c[0]=0.f; c[1]=0.f; c[2]=0.f; c[3]=0.f;
      const short8 b0 = *(const short8*)((const char*)KV + (ct*16 + mrow)*(KSTR*2) + q4*16);
      const short8 b1 = *(const short8*)((const char*)KV + (ct*16 + mrow)*(KSTR*2) + 64 + q4*16);
      c = __builtin_amdgcn_mfma_f32_16x16x32_bf16(aq0, b0, c, 0, 0, 0);
      c = __builtin_amdgcn_mfma_f32_16x16x32_bf16(aq1, b1, c, 0, 0, 0);
      cacc[ct] = c;
    }
    #pragma unroll
    for (int r = 0; r < 4; ++r) {
      const int iq = q0 + rb + q4*4 + r;
      float m = -1e30f;
      #pragma unroll
      for (int ct = 0; ct < NKT; ++ct) {
        const int jj = ct*16 + mrow;
        const int j = k0 + jj;
        const bool ok = (jj < nk) && (j >= iq - WIN) && (j <= iq + WIN);
        const float s = ok ? cacc[ct][r] * 0.125f : -1e30f;
        cacc[ct][r] = s;
        m = fmaxf(m, s);
      }
      m = fmaxf(m, __shfl_xor(m, 1, 64));
      m = fmaxf(m, __shfl_xor(m, 2, 64));
      m = fmaxf(m, __shfl_xor(m, 4, 64));
      m = fmaxf(m, __shfl_xor(m, 8, 64));
      float s = 0.f;
      #pragma unroll
      for (int ct = 0; ct < NKT; ++ct) {
        const float e = __expf(cacc[ct][r] - m);
        cacc[ct][r] = e;
        s += e;
      }
      s += __shfl_xor(s, 1, 64);
      s += __shfl_xor(s, 2, 64);
      s += __shfl_xor(s, 4, 64);
      s += __shfl_xor(s, 8, 64);
      const float rinv = 1.0f / s;
      #pragma unroll
      for (int ct = 0; ct < NKT; ++ct)
        Ps[(rb + q4*4 + r) * PSTR + ct*16 + mrow] = f2bf(cacc[ct][r] * rinv);
    }
  }
  __syncthreads();

  {
    uint16_t* Vt = KV;
    const int gg = t & 7;
    for (int j = t >> 3; j < NKP; j += 32) {
      if (j < nk) {
        const uint4 v = *(const uint4*)(qkv + (size_t)(b*SEQ + k0 + j) * 3072 + 2048 + hh*64 + gg*8);
        uint16_t e[8] = { (uint16_t)(v.x & 0xffff), (uint16_t)(v.x >> 16),
                          (uint16_t)(v.y & 0xffff), (uint16_t)(v.y >> 16),
                          (uint16_t)(v.z & 0xffff), (uint16_t)(v.z >> 16),
                          (uint16_t)(v.w & 0xffff), (uint16_t)(v.w >> 16) };
        #pragma unroll
        for (int dd = 0; dd < 8; ++dd) Vt[(gg*8 + dd) * PSTR + j] = e[dd];
      } else {
        #pragma unroll
        for (int dd = 0; dd < 8; ++dd) Vt[(gg*8 + dd) * PSTR + j] = 0;
      }
    }
  }
  __syncthreads();

  {
    const uint16_t* Vt = KV;
    const int mrow = l & 15, q4 = l >> 4;
    const int rt = w & 1, dt0 = (w >> 1) * 2;
    f32x4 o0, o1;
    #pragma unroll
    for (int e = 0; e < 4; ++e) { o0[e] = 0.f; o1[e] = 0.f; }
    #pragma unroll
    for (int ks = 0; ks < 9; ++ks) {
      const short8 a  = *(const short8*)((const char*)Ps + (rt*16 + mrow)*(PSTR*2) + ks*64 + q4*16);
      const short8 v0 = *(const short8*)((const char*)Vt + ((dt0  )*16 + mrow)*(PSTR*2) + ks*64 + q4*16);
      const short8 v1 = *(const short8*)((const char*)Vt + ((dt0+1)*16 + mrow)*(PSTR*2) + ks*64 + q4*16);
      o0 = __builtin_amdgcn_mfma_f32_16x16x32_bf16(a, v0, o0, 0, 0, 0);
      o1 = __builtin_amdgcn_mfma_f32_16x16x32_bf16(a, v1, o1, 0, 0, 0);
    }
    #pragma unroll
    for (int r = 0; r < 4; ++r) {
      const int iq = q0 + rt*16 + q4*4 + r;
      const size_t rowoff = (size_t)(b*SEQ + iq) * DMODEL + hh*64;
      out[rowoff + (dt0  )*16 + mrow] = f2bf(o0[r]);
      out[rowoff + (dt0+1)*16 + mrow] = f2bf(o1[r]);
    }
  }
}

// --------------------------------- launch ----------------------------------
extern "C" void kernel_launch(void* const* d_in, const int* in_sizes, int n_in,
                              void* d_out, int out_size, void* d_ws, size_t ws_size,
                              hipStream_t stream)
{
  const float* x    = (const float*)d_in[0];
  const float* ln1g = (const float*)d_in[1];
  const float* ln1b = (const float*)d_in[2];
  const float* wqkv = (const float*)d_in[3];
  const float* wout = (const float*)d_in[4];
  const float* bout = (const float*)d_in[5];
  const float* ln2g = (const float*)d_in[6];
  const float* ln2b = (const float*)d_in[7];
  const float* wff1 = (const float*)d_in[8];
  const float* bff1 = (const float*)d_in[9];
  const float* wff2 = (const float*)d_in[10];
  const float* bff2 = (const float*)d_in[11];
  float* out = (float*)d_out;

  char* ws = (char*)d_ws;
  const size_t MB = (size_t)1 << 20;
  // Persist-until-dead regions (ws proven >= 97 MB by round-3 diagnostic):
  uint16_t* Wqkv = (uint16_t*)(ws);            //  0-6   (dead after qkv gemm)
  uint16_t* Wout = (uint16_t*)(ws +  6*MB);    //  6-8   (dead after out-proj)
  uint16_t* Wff1 = (uint16_t*)(ws +  8*MB);    //  8-16  (dead after ff1)
  uint16_t* Wff2 = (uint16_t*)(ws + 16*MB);    // 16-24  (live until ff2)
  uint16_t* QKV  = (uint16_t*)(ws + 24*MB);    // 24-48  (dead after attn)
  uint16_t* H1   = (uint16_t*)(ws + 48*MB);    // 48-56  h1 -> attn_out
  uint16_t* AT   = H1;
  float*    X2f  = (float*)   (ws + 56*MB);    // 56-72  fp32 (live to end)
  uint16_t* H2   = (uint16_t*)(ws + 72*MB);    // 72-80  (dead after ff1)
  // out-proj fp32 partials (during out-proj/combine):
  float*    OP0  = (float*)   (ws + 24*MB);    // 24-40  (ex-QKV)
  float*    OP1  = (float*)   (ws + 80*MB);    // 80-96
  uint16_t* FF1  = (uint16_t*)(ws + 24*MB);    // 24-56  (after combine)
  // FF2 bf16 partials (after ff1; all source regions dead):
  uint16_t* FP0  = (uint16_t*)(ws);            //  0-8
  uint16_t* FP1  = (uint16_t*)(ws +  8*MB);    //  8-16
  uint16_t* FP2  = (uint16_t*)(ws + 72*MB);    // 72-80
  uint16_t* FP3  = (uint16_t*)(ws + 80*MB);    // 80-88
  // high-water: 96 MB

  // 0) weights fp32 -> bf16
  cvt4_kernel<<<12288, 256, 0, stream>>>(wqkv, wout, wff1, wff2, Wqkv, Wout, Wff1, Wff2);
  // 1) h1 = LN1(x)
  ln_kernel<<<MTOK, 256, 0, stream>>>(x, ln1g, ln1b, H1);
  // 2) qkv = h1 @ w_qkv^T                       (768 blocks)
  gemm_bt<0><<<dim3(3072/128, MTOK/128), 256, 0, stream>>>(H1, Wqkv, nullptr, QKV, MTOK, 3072, DMODEL);
  // 3) attn_out = local_attention(qkv)
  attn_kernel<<<dim3(SEQ/TQ, NHEAD, NB), 256, 0, stream>>>(QKV, AT);
  // 4) out-proj split-K=2 -> fp32 partials      (1024 blocks, 4/CU)
  gemm_sk64<<<dim3(DMODEL/64, MTOK/128, 2), 256, 0, stream>>>(AT, Wout, OP0, OP1, MTOK, DMODEL, DMODEL, DMODEL/2);
  // 5) x2 = p0+p1+b_out+x; h2 = LN2(x2)         (fused)
  combine_ln2_kernel<<<MTOK, 256, 0, stream>>>(OP0, OP1, x, bout, ln2g, ln2b, X2f, H2);
  // 6) ff1 = gelu(h2 @ w_ff1^T + b_ff1)         (1024 blocks)
  gemm_bt<2><<<dim3(FFDIM/128, MTOK/128), 256, 0, stream>>>(H2, Wff1, bff1, FF1, MTOK, FFDIM, DMODEL);
  // 7) FF2 split-K=4 -> bf16 partials           (1024 blocks, 4/CU)
  gemm_sk128<<<dim3(DMODEL/128, MTOK/128, 4), 256, 0, stream>>>(FF1, Wff2, FP0, FP1, FP2, FP3, MTOK, DMODEL, FFDIM, FFDIM/4);
  // 8) out = sum(partials) + b_ff2 + x2
  combine_ff2_kernel<<<MTOK, 256, 0, stream>>>(FP0, FP1, FP2, FP3, bff2, X2f, out);
}

// Round 7
// 385.142 us; speedup vs baseline: 1.0244x; 1.0244x over previous
//
#include <hip/hip_runtime.h>
#include <stdint.h>

#define SEQ    2048
#define NB     2
#define DMODEL 1024
#define NHEAD  16
#define HDIM   64
#define FFDIM  4096
#define WIN    128
#define MTOK   (NB*SEQ)   // 4096 tokens

typedef short short8 __attribute__((ext_vector_type(8)));  // 8 bf16 (4 VGPRs)
typedef float f32x4  __attribute__((ext_vector_type(4)));

__device__ __forceinline__ float bf2f(uint16_t h){ return __uint_as_float(((uint32_t)h) << 16); }
__device__ __forceinline__ uint16_t f2bf(float f){           // RNE f32->bf16
  uint32_t u = __float_as_uint(f);
  u += 0x7fffu + ((u >> 16) & 1u);
  return (uint16_t)(u >> 16);
}
__device__ __forceinline__ int sw4(int r){ return (r ^ (r >> 2)) & 3; }

// tanh-form GELU, branch-free (~12 VALU vs erff's ~40-60 divergent).
// max |delta| vs exact erf-GELU ~3e-3; clamp keeps exp finite (no inf/inf).
__device__ __forceinline__ float gelu_f(float v){
  float u = 0.7978845608028654f * v * (1.0f + 0.044715f * v * v);
  u = fminf(fmaxf(u, -10.0f), 10.0f);
  const float e = __expf(2.0f * u);
  const float th = (e - 1.0f) / (e + 1.0f);
  return 0.5f * v * (1.0f + th);
}

__device__ __forceinline__ void gl_lds16(const void* g, void* l) {
  __builtin_amdgcn_global_load_lds((const __attribute__((address_space(1))) void*)g,
                                   (__attribute__((address_space(3))) void*)l, 16, 0, 0);
}

// ---------- fused fp32->bf16 weight convert (wqkv|wout|wff1|wff2) ----------
__global__ __launch_bounds__(256) void cvt4_kernel(
    const float* __restrict__ s0, const float* __restrict__ s1,
    const float* __restrict__ s2, const float* __restrict__ s3,
    uint16_t* __restrict__ d0, uint16_t* __restrict__ d1,
    uint16_t* __restrict__ d2, uint16_t* __restrict__ d3)
{
  size_t i = (size_t)blockIdx.x * 256 + threadIdx.x;   // float4 index; 3M total
  const float* s; uint16_t* d; size_t off;
  if      (i <  768*1024) { s = s0; d = d0; off = i; }
  else if (i < 1024*1024) { s = s1; d = d1; off = i -  768*1024; }
  else if (i < 2048*1024) { s = s2; d = d2; off = i - 1024*1024; }
  else                    { s = s3; d = d3; off = i - 2048*1024; }
  const float4 v = ((const float4*)s)[off];
  uint2 o;
  o.x = (uint32_t)f2bf(v.x) | ((uint32_t)f2bf(v.y) << 16);
  o.y = (uint32_t)f2bf(v.z) | ((uint32_t)f2bf(v.w) << 16);
  ((uint2*)d)[off] = o;
}

// -------- LayerNorm: fp32 in -> bf16 out; one row (1024) per block ---------
__global__ __launch_bounds__(256) void ln_kernel(const float* __restrict__ x,
                                                 const float* __restrict__ g,
                                                 const float* __restrict__ b,
                                                 uint16_t* __restrict__ y)
{
  const int row = blockIdx.x;
  const int t = threadIdx.x;
  const float4 v = ((const float4*)(x + (size_t)row * DMODEL))[t];
  float s1 = v.x + v.y + v.z + v.w;
  float s2 = v.x*v.x + v.y*v.y + v.z*v.z + v.w*v.w;
  #pragma unroll
  for (int off = 32; off; off >>= 1) { s1 += __shfl_xor(s1, off, 64); s2 += __shfl_xor(s2, off, 64); }
  __shared__ float red[8];
  const int w = t >> 6;
  if ((t & 63) == 0) { red[w] = s1; red[4+w] = s2; }
  __syncthreads();
  s1 = red[0]+red[1]+red[2]+red[3];
  s2 = red[4]+red[5]+red[6]+red[7];
  const float mu = s1 * (1.0f/DMODEL);
  const float var = s2 * (1.0f/DMODEL) - mu*mu;
  const float rs = rsqrtf(var + 1e-5f);
  const float4 gv = ((const float4*)g)[t];
  const float4 bv = ((const float4*)b)[t];
  uint2 o;
  o.x = (uint32_t)f2bf((v.x-mu)*rs*gv.x + bv.x) | ((uint32_t)f2bf((v.y-mu)*rs*gv.y + bv.y) << 16);
  o.y = (uint32_t)f2bf((v.z-mu)*rs*gv.z + bv.z) | ((uint32_t)f2bf((v.w-mu)*rs*gv.w + bv.w) << 16);
  ((uint2*)(y + (size_t)row * DMODEL))[t] = o;
}

// ---------- GEMM 128x128: C[M,N] = A[M,K] @ Bm[N,K]^T (+epilogue) ----------
// EPI: 0 none (bf16 C), 2 +bias then GELU (bf16 C)
template<int EPI>
__global__ __launch_bounds__(256) void gemm_bt(
    const uint16_t* __restrict__ A, const uint16_t* __restrict__ Bm,
    const float* __restrict__ bias, uint16_t* __restrict__ C,
    int M, int N, int K)
{
  __shared__ __align__(16) uint16_t As[128*32];
  __shared__ __align__(16) uint16_t Bs[128*32];
  const int t = threadIdx.x;
  const int l = t & 63;
  const int w = t >> 6;
  const int row0 = blockIdx.y * 128;
  const int col0 = blockIdx.x * 128;
  const int wm = (w >> 1) * 64, wn = (w & 1) * 64;

  f32x4 acc[4][4];
  #pragma unroll
  for (int i = 0; i < 4; ++i)
    #pragma unroll
    for (int j = 0; j < 4; ++j)
      #pragma unroll
      for (int e = 0; e < 4; ++e) acc[i][j][e] = 0.0f;

  const int sr = t >> 2, ss = t & 3;
  const int sg = ss ^ sw4(sr);
  const uint16_t* aG = A  + (size_t)(row0 + sr) * K + sg * 8;
  const uint16_t* bG = Bm + (size_t)(col0 + sr) * K + sg * 8;
  char* aL = (char*)As + t * 16;
  char* bL = (char*)Bs + t * 16;
  const int mrow = l & 15;
  const int slot = (l >> 4) ^ sw4(mrow);

  for (int k0 = 0; k0 < K; k0 += 32) {
    gl_lds16(aG + k0,                   aL);
    gl_lds16(aG + k0 + (size_t)64 * K,  aL + 4096);
    gl_lds16(bG + k0,                   bL);
    gl_lds16(bG + k0 + (size_t)64 * K,  bL + 4096);
    __syncthreads();
    short8 af[4], bfr[4];
    #pragma unroll
    for (int mi = 0; mi < 4; ++mi)
      af[mi] = *(const short8*)((const char*)As + (wm + mi*16 + mrow) * 64 + slot * 16);
    #pragma unroll
    for (int ni = 0; ni < 4; ++ni)
      bfr[ni] = *(const short8*)((const char*)Bs + (wn + ni*16 + mrow) * 64 + slot * 16);
    #pragma unroll
    for (int mi = 0; mi < 4; ++mi)
      #pragma unroll
      for (int ni = 0; ni < 4; ++ni)
        acc[mi][ni] = __builtin_amdgcn_mfma_f32_16x16x32_bf16(af[mi], bfr[ni], acc[mi][ni], 0, 0, 0);
    __syncthreads();
  }

  const int crow = (l >> 4) * 4;   // C/D: col = lane&15, row = (lane>>4)*4 + reg
  float bv[4];
  #pragma unroll
  for (int ni = 0; ni < 4; ++ni)
    bv[ni] = (EPI != 0) ? bias[col0 + wn + ni*16 + mrow] : 0.0f;
  #pragma unroll
  for (int mi = 0; mi < 4; ++mi) {
    #pragma unroll
    for (int r = 0; r < 4; ++r) {
      const int row = row0 + wm + mi*16 + crow + r;
      #pragma unroll
      for (int ni = 0; ni < 4; ++ni) {
        const int col = col0 + wn + ni*16 + mrow;
        float v = acc[mi][ni][r] + bv[ni];
        if (EPI == 2) v = gelu_f(v);
        C[(size_t)row * N + col] = f2bf(v);
      }
    }
  }
}

// ------- split-K GEMM, 128x64 tile: fp32 partial, no bias (out-proj) -------
__global__ __launch_bounds__(256) void gemm_sk64(
    const uint16_t* __restrict__ A, const uint16_t* __restrict__ Bm,
    float* __restrict__ P0, float* __restrict__ P1,
    int M, int N, int K, int KS)
{
  __shared__ __align__(16) uint16_t As[128*32];
  __shared__ __align__(16) uint16_t Bs[64*32];
  const int t = threadIdx.x;
  const int l = t & 63;
  const int w = t >> 6;
  const int row0 = blockIdx.y * 128;
  const int col0 = blockIdx.x * 64;
  const int kbase = blockIdx.z * KS;
  float* P = blockIdx.z ? P1 : P0;
  const int wm = (w >> 1) * 64, wn = (w & 1) * 32;

  f32x4 acc[4][2];
  #pragma unroll
  for (int i = 0; i < 4; ++i)
    #pragma unroll
    for (int j = 0; j < 2; ++j)
      #pragma unroll
      for (int e = 0; e < 4; ++e) acc[i][j][e] = 0.0f;

  const int sr = t >> 2, ss = t & 3;
  const int sg = ss ^ sw4(sr);
  const uint16_t* aG = A  + (size_t)(row0 + sr) * K + kbase + sg * 8;
  const uint16_t* bG = Bm + (size_t)(col0 + sr) * K + kbase + sg * 8;
  char* aL = (char*)As + t * 16;
  char* bL = (char*)Bs + t * 16;
  const int mrow = l & 15;
  const int slot = (l >> 4) ^ sw4(mrow);

  for (int k0 = 0; k0 < KS; k0 += 32) {
    gl_lds16(aG + k0,                   aL);
    gl_lds16(aG + k0 + (size_t)64 * K,  aL + 4096);
    gl_lds16(bG + k0,                   bL);
    __syncthreads();
    short8 af[4], bfr[2];
    #pragma unroll
    for (int mi = 0; mi < 4; ++mi)
      af[mi] = *(const short8*)((const char*)As + (wm + mi*16 + mrow) * 64 + slot * 16);
    #pragma unroll
    for (int ni = 0; ni < 2; ++ni)
      bfr[ni] = *(const short8*)((const char*)Bs + (wn + ni*16 + mrow) * 64 + slot * 16);
    #pragma unroll
    for (int mi = 0; mi < 4; ++mi)
      #pragma unroll
      for (int ni = 0; ni < 2; ++ni)
        acc[mi][ni] = __builtin_amdgcn_mfma_f32_16x16x32_bf16(af[mi], bfr[ni], acc[mi][ni], 0, 0, 0);
    __syncthreads();
  }

  const int crow = (l >> 4) * 4;
  #pragma unroll
  for (int mi = 0; mi < 4; ++mi)
    #pragma unroll
    for (int r = 0; r < 4; ++r) {
      const int row = row0 + wm + mi*16 + crow + r;
      #pragma unroll
      for (int ni = 0; ni < 2; ++ni)
        P[(size_t)row * N + col0 + wn + ni*16 + mrow] = acc[mi][ni][r];
    }
}

// ------- split-K GEMM, 128x128 tile: bf16 partial, no bias (FF2) -----------
__global__ __launch_bounds__(256) void gemm_sk128(
    const uint16_t* __restrict__ A, const uint16_t* __restrict__ Bm,
    uint16_t* __restrict__ P0, uint16_t* __restrict__ P1,
    uint16_t* __restrict__ P2, uint16_t* __restrict__ P3,
    int M, int N, int K, int KS)
{
  __shared__ __align__(16) uint16_t As[128*32];
  __shared__ __align__(16) uint16_t Bs[128*32];
  const int t = threadIdx.x;
  const int l = t & 63;
  const int w = t >> 6;
  const int row0 = blockIdx.y * 128;
  const int col0 = blockIdx.x * 128;
  const int z = blockIdx.z;
  const int kbase = z * KS;
  uint16_t* P = (z < 2) ? (z ? P1 : P0) : (z == 2 ? P2 : P3);
  const int wm = (w >> 1) * 64, wn = (w & 1) * 64;

  f32x4 acc[4][4];
  #pragma unroll
  for (int i = 0; i < 4; ++i)
    #pragma unroll
    for (int j = 0; j < 4; ++j)
      #pragma unroll
      for (int e = 0; e < 4; ++e) acc[i][j][e] = 0.0f;

  const int sr = t >> 2, ss = t & 3;
  const int sg = ss ^ sw4(sr);
  const uint16_t* aG = A  + (size_t)(row0 + sr) * K + kbase + sg * 8;
  const uint16_t* bG = Bm + (size_t)(col0 + sr) * K + kbase + sg * 8;
  char* aL = (char*)As + t * 16;
  char* bL = (char*)Bs + t * 16;
  const int mrow = l & 15;
  const int slot = (l >> 4) ^ sw4(mrow);

  for (int k0 = 0; k0 < KS; k0 += 32) {
    gl_lds16(aG + k0,                   aL);
    gl_lds16(aG + k0 + (size_t)64 * K,  aL + 4096);
    gl_lds16(bG + k0,                   bL);
    gl_lds16(bG + k0 + (size_t)64 * K,  bL + 4096);
    __syncthreads();
    short8 af[4], bfr[4];
    #pragma unroll
    for (int mi = 0; mi < 4; ++mi)
      af[mi] = *(const short8*)((const char*)As + (wm + mi*16 + mrow) * 64 + slot * 16);
    #pragma unroll
    for (int ni = 0; ni < 4; ++ni)
      bfr[ni] = *(const short8*)((const char*)Bs + (wn + ni*16 + mrow) * 64 + slot * 16);
    #pragma unroll
    for (int mi = 0; mi < 4; ++mi)
      #pragma unroll
      for (int ni = 0; ni < 4; ++ni)
        acc[mi][ni] = __builtin_amdgcn_mfma_f32_16x16x32_bf16(af[mi], bfr[ni], acc[mi][ni], 0, 0, 0);
    __syncthreads();
  }

  const int crow = (l >> 4) * 4;
  #pragma unroll
  for (int mi = 0; mi < 4; ++mi)
    #pragma unroll
    for (int r = 0; r < 4; ++r) {
      const int row = row0 + wm + mi*16 + crow + r;
      #pragma unroll
      for (int ni = 0; ni < 4; ++ni)
        P[(size_t)row * N + col0 + wn + ni*16 + mrow] = f2bf(acc[mi][ni][r]);
    }
}

// ---- combine out-proj partials + bias + residual, then LN2, in one pass ---
__global__ __launch_bounds__(256) void combine_ln2_kernel(
    const float* __restrict__ p0, const float* __restrict__ p1,
    const float* __restrict__ x,  const float* __restrict__ bout,
    const float* __restrict__ g,  const float* __restrict__ b,
    float* __restrict__ X2f, uint16_t* __restrict__ H2)
{
  const int row = blockIdx.x;
  const int t = threadIdx.x;
  const size_t off = (size_t)row * (DMODEL/4) + t;
  const float4 a0 = ((const float4*)p0)[off];
  const float4 a1 = ((const float4*)p1)[off];
  const float4 xv = ((const float4*)x)[off];
  const float4 bo = ((const float4*)bout)[t];
  float4 v;
  v.x = a0.x + a1.x + xv.x + bo.x;
  v.y = a0.y + a1.y + xv.y + bo.y;
  v.z = a0.z + a1.z + xv.z + bo.z;
  v.w = a0.w + a1.w + xv.w + bo.w;
  ((float4*)X2f)[off] = v;
  float s1 = v.x + v.y + v.z + v.w;
  float s2 = v.x*v.x + v.y*v.y + v.z*v.z + v.w*v.w;
  #pragma unroll
  for (int o = 32; o; o >>= 1) { s1 += __shfl_xor(s1, o, 64); s2 += __shfl_xor(s2, o, 64); }
  __shared__ float red[8];
  const int w = t >> 6;
  if ((t & 63) == 0) { red[w] = s1; red[4+w] = s2; }
  __syncthreads();
  s1 = red[0]+red[1]+red[2]+red[3];
  s2 = red[4]+red[5]+red[6]+red[7];
  const float mu = s1 * (1.0f/DMODEL);
  const float var = s2 * (1.0f/DMODEL) - mu*mu;
  const float rs = rsqrtf(var + 1e-5f);
  const float4 gv = ((const float4*)g)[t];
  const float4 bv = ((const float4*)b)[t];
  uint2 o;
  o.x = (uint32_t)f2bf((v.x-mu)*rs*gv.x + bv.x) | ((uint32_t)f2bf((v.y-mu)*rs*gv.y + bv.y) << 16);
  o.y = (uint32_t)f2bf((v.z-mu)*rs*gv.z + bv.z) | ((uint32_t)f2bf((v.w-mu)*rs*gv.w + bv.w) << 16);
  ((uint2*)(H2 + (size_t)row * DMODEL))[t] = o;
}

// ---------- combine FF2 bf16 partials + bias + residual -> fp32 out --------
__global__ __launch_bounds__(256) void combine_ff2_kernel(
    const uint16_t* __restrict__ p0, const uint16_t* __restrict__ p1,
    const uint16_t* __restrict__ p2, const uint16_t* __restrict__ p3,
    const float* __restrict__ bff2, const float* __restrict__ X2f,
    float* __restrict__ out)
{
  const int row = blockIdx.x;
  const int t = threadIdx.x;
  const size_t eoff = (size_t)row * DMODEL + t * 4;
  const uint2 u0 = *(const uint2*)(p0 + eoff);
  const uint2 u1 = *(const uint2*)(p1 + eoff);
  const uint2 u2 = *(const uint2*)(p2 + eoff);
  const uint2 u3 = *(const uint2*)(p3 + eoff);
  const float4 xv = ((const float4*)X2f)[(size_t)row * (DMODEL/4) + t];
  const float4 bo = ((const float4*)bff2)[t];
  float4 v;
  v.x = bf2f((uint16_t)(u0.x & 0xffff)) + bf2f((uint16_t)(u1.x & 0xffff))
      + bf2f((uint16_t)(u2.x & 0xffff)) + bf2f((uint16_t)(u3.x & 0xffff)) + bo.x + xv.x;
  v.y = bf2f((uint16_t)(u0.x >> 16)) + bf2f((uint16_t)(u1.x >> 16))
      + bf2f((uint16_t)(u2.x >> 16)) + bf2f((uint16_t)(u3.x >> 16)) + bo.y + xv.y;
  v.z = bf2f((uint16_t)(u0.y & 0xffff)) + bf2f((uint16_t)(u1.y & 0xffff))
      + bf2f((uint16_t)(u2.y & 0xffff)) + bf2f((uint16_t)(u3.y & 0xffff)) + bo.z + xv.z;
  v.w = bf2f((uint16_t)(u0.y >> 16)) + bf2f((uint16_t)(u1.y >> 16))
      + bf2f((uint16_t)(u2.y >> 16)) + bf2f((uint16_t)(u3.y >> 16)) + bo.w + xv.w;
  ((float4*)out)[(size_t)row * (DMODEL/4) + t] = v;
}

// --------------------- local-window attention (MFMA) -----------------------
#define TQ    32
#define NKT   18
#define NKP   (NKT*16)   // 288 key slots
#define KSTR  72         // Qs/KV row stride (bf16)
#define PSTR  296        // Ps/Vt row stride (bf16)

__global__ __launch_bounds__(256) void attn_kernel(const uint16_t* __restrict__ qkv,
                                                   uint16_t* __restrict__ out)
{
  __shared__ uint16_t Qs[TQ * KSTR];
  __shared__ uint16_t Ps[TQ * PSTR];
  __shared__ uint16_t KV[NKP * KSTR];
  const int t = threadIdx.x, l = t & 63, w = t >> 6;
  const int b = blockIdx.z, hh = blockIdx.y, q0 = blockIdx.x * TQ;
  const int k0 = (q0 - WIN > 0) ? (q0 - WIN) : 0;
  const int kend_ = q0 + TQ + WIN;
  const int kend = (kend_ < SEQ) ? kend_ : SEQ;
  const int nk = kend - k0;

  {
    const int r = t >> 3, gg = t & 7;
    const uint4 qv = *(const uint4*)(qkv + (size_t)(b*SEQ + q0 + r) * 3072 + hh*64 + gg*8);
    *(uint4*)((char*)Qs + r*(KSTR*2) + gg*16) = qv;
    for (int j = r; j < NKP; j += 32) {
      uint4 kv; kv.x = 0; kv.y = 0; kv.z = 0; kv.w = 0;
      if (j < nk)
        kv = *(const uint4*)(qkv + (size_t)(b*SEQ + k0 + j) * 3072 + 1024 + hh*64 + gg*8);
      *(uint4*)((char*)KV + j*(KSTR*2) + gg*16) = kv;
    }
  }
  __syncthreads();

  if (w < 2) {
    const int rb = w * 16;
    const int mrow = l & 15, q4 = l >> 4;
    const short8 aq0 = *(const short8*)((const char*)Qs + (rb + mrow)*(KSTR*2) + q4*16);
    const short8 aq1 = *(const short8*)((const char*)Qs + (rb + mrow)*(KSTR*2) + 64 + q4*16);
    f32x4 cacc[NKT];
    #pragma unroll
    for (int ct = 0; ct < NKT; ++ct) {
      f32x4 c; c[0]=0.f; c[1]=0.f; c[2]=0.f; c[3]=0.f;
      const short8 b0 = *(const short8*)((const char*)KV + (ct*16 + mrow)*(KSTR*2) + q4*16);
      const short8 b1 = *(const short8*)((const char*)KV + (ct*16 + mrow)*(KSTR*2) + 64 + q4*16);
      c = __builtin_amdgcn_mfma_f32_16x16x32_bf16(aq0, b0, c, 0, 0, 0);
      c = __builtin_amdgcn_mfma_f32_16x16x32_bf16(aq1, b1, c, 0, 0, 0);
      cacc[ct] = c;
    }
    #pragma unroll
    for (int r = 0; r < 4; ++r) {
      const int iq = q0 + rb + q4*4 + r;
      float m = -1e30f;
      #pragma unroll
      for (int ct = 0; ct < NKT; ++ct) {
        const int jj = ct*16 + mrow;
        const int j = k0 + jj;
        const bool ok = (jj < nk) && (j >= iq - WIN) && (j <= iq + WIN);
        const float s = ok ? cacc[ct][r] * 0.125f : -1e30f;
        cacc[ct][r] = s;
        m = fmaxf(m, s);
      }
      m = fmaxf(m, __shfl_xor(m, 1, 64));
      m = fmaxf(m, __shfl_xor(m, 2, 64));
      m = fmaxf(m, __shfl_xor(m, 4, 64));
      m = fmaxf(m, __shfl_xor(m, 8, 64));
      float s = 0.f;
      #pragma unroll
      for (int ct = 0; ct < NKT; ++ct) {
        const float e = __expf(cacc[ct][r] - m);
        cacc[ct][r] = e;
        s += e;
      }
      s += __shfl_xor(s, 1, 64);
      s += __shfl_xor(s, 2, 64);
      s += __shfl_xor(s, 4, 64);
      s += __shfl_xor(s, 8, 64);
      const float rinv = 1.0f / s;
      #pragma unroll
      for (int ct = 0; ct < NKT; ++ct)
        Ps[(rb + q4*4 + r) * PSTR + ct*16 + mrow] = f2bf(cacc[ct][r] * rinv);
    }
  }
  __syncthreads();

  {
    uint16_t* Vt = KV;
    const int gg = t & 7;
    for (int j = t >> 3; j < NKP; j += 32) {
      if (j < nk) {
        const uint4 v = *(const uint4*)(qkv + (size_t)(b*SEQ + k0 + j) * 3072 + 2048 + hh*64 + gg*8);
        uint16_t e[8] = { (uint16_t)(v.x & 0xffff), (uint16_t)(v.x >> 16),
                          (uint16_t)(v.y & 0xffff), (uint16_t)(v.y >> 16),
                          (uint16_t)(v.z & 0xffff), (uint16_t)(v.z >> 16),
                          (uint16_t)(v.w & 0xffff), (uint16_t)(v.w >> 16) };
        #pragma unroll
        for (int dd = 0; dd < 8; ++dd) Vt[(gg*8 + dd) * PSTR + j] = e[dd];
      } else {
        #pragma unroll
        for (int dd = 0; dd < 8; ++dd) Vt[(gg*8 + dd) * PSTR + j] = 0;
      }
    }
  }
  __syncthreads();

  {
    const uint16_t* Vt = KV;
    const int mrow = l & 15, q4 = l >> 4;
    const int rt = w & 1, dt0 = (w >> 1) * 2;
    f32x4 o0, o1;
    #pragma unroll
    for (int e = 0; e < 4; ++e) { o0[e] = 0.f; o1[e] = 0.f; }
    #pragma unroll
    for (int ks = 0; ks < 9; ++ks) {
      const short8 a  = *(const short8*)((const char*)Ps + (rt*16 + mrow)*(PSTR*2) + ks*64 + q4*16);
      const short8 v0 = *(const short8*)((const char*)Vt + ((dt0  )*16 + mrow)*(PSTR*2) + ks*64 + q4*16);
      const short8 v1 = *(const short8*)((const char*)Vt + ((dt0+1)*16 + mrow)*(PSTR*2) + ks*64 + q4*16);
      o0 = __builtin_amdgcn_mfma_f32_16x16x32_bf16(a, v0, o0, 0, 0, 0);
      o1 = __builtin_amdgcn_mfma_f32_16x16x32_bf16(a, v1, o1, 0, 0, 0);
    }
    #pragma unroll
    for (int r = 0; r < 4; ++r) {
      const int iq = q0 + rt*16 + q4*4 + r;
      const size_t rowoff = (size_t)(b*SEQ + iq) * DMODEL + hh*64;
      out[rowoff + (dt0  )*16 + mrow] = f2bf(o0[r]);
      out[rowoff + (dt0+1)*16 + mrow] = f2bf(o1[r]);
    }
  }
}

// --------------------------------- launch ----------------------------------
extern "C" void kernel_launch(void* const* d_in, const int* in_sizes, int n_in,
                              void* d_out, int out_size, void* d_ws, size_t ws_size,
                              hipStream_t stream)
{
  const float* x    = (const float*)d_in[0];
  const float* ln1g = (const float*)d_in[1];
  const float* ln1b = (const float*)d_in[2];
  const float* wqkv = (const float*)d_in[3];
  const float* wout = (const float*)d_in[4];
  const float* bout = (const float*)d_in[5];
  const float* ln2g = (const float*)d_in[6];
  const float* ln2b = (const float*)d_in[7];
  const float* wff1 = (const float*)d_in[8];
  const float* bff1 = (const float*)d_in[9];
  const float* wff2 = (const float*)d_in[10];
  const float* bff2 = (const float*)d_in[11];
  float* out = (float*)d_out;

  char* ws = (char*)d_ws;
  const size_t MB = (size_t)1 << 20;
  uint16_t* Wqkv = (uint16_t*)(ws);            //  0-6   (dead after qkv gemm)
  uint16_t* Wout = (uint16_t*)(ws +  6*MB);    //  6-8   (dead after out-proj)
  uint16_t* Wff1 = (uint16_t*)(ws +  8*MB);    //  8-16  (dead after ff1)
  uint16_t* Wff2 = (uint16_t*)(ws + 16*MB);    // 16-24  (live until ff2)
  uint16_t* QKV  = (uint16_t*)(ws + 24*MB);    // 24-48  (dead after attn)
  uint16_t* H1   = (uint16_t*)(ws + 48*MB);    // 48-56  h1 -> attn_out
  uint16_t* AT   = H1;
  float*    X2f  = (float*)   (ws + 56*MB);    // 56-72  fp32 (live to end)
  uint16_t* H2   = (uint16_t*)(ws + 72*MB);    // 72-80  (dead after ff1)
  float*    OP0  = (float*)   (ws + 24*MB);    // 24-40  (ex-QKV)
  float*    OP1  = (float*)   (ws + 80*MB);    // 80-96
  uint16_t* FF1  = (uint16_t*)(ws + 24*MB);    // 24-56  (after combine)
  uint16_t* FP0  = (uint16_t*)(ws);            //  0-8
  uint16_t* FP1  = (uint16_t*)(ws +  8*MB);    //  8-16
  uint16_t* FP2  = (uint16_t*)(ws + 72*MB);    // 72-80
  uint16_t* FP3  = (uint16_t*)(ws + 80*MB);    // 80-88
  // high-water: 96 MB

  // 0) weights fp32 -> bf16
  cvt4_kernel<<<12288, 256, 0, stream>>>(wqkv, wout, wff1, wff2, Wqkv, Wout, Wff1, Wff2);
  // 1) h1 = LN1(x)
  ln_kernel<<<MTOK, 256, 0, stream>>>(x, ln1g, ln1b, H1);
  // 2) qkv = h1 @ w_qkv^T                       (768 blocks)
  gemm_bt<0><<<dim3(3072/128, MTOK/128), 256, 0, stream>>>(H1, Wqkv, nullptr, QKV, MTOK, 3072, DMODEL);
  // 3) attn_out = local_attention(qkv)
  attn_kernel<<<dim3(SEQ/TQ, NHEAD, NB), 256, 0, stream>>>(QKV, AT);
  // 4) out-proj split-K=2 -> fp32 partials      (1024 blocks, 4/CU)
  gemm_sk64<<<dim3(DMODEL/64, MTOK/128, 2), 256, 0, stream>>>(AT, Wout, OP0, OP1, MTOK, DMODEL, DMODEL, DMODEL/2);
  // 5) x2 = p0+p1+b_out+x; h2 = LN2(x2)         (fused)
  combine_ln2_kernel<<<MTOK, 256, 0, stream>>>(OP0, OP1, x, bout, ln2g, ln2b, X2f, H2);
  // 6) ff1 = gelu(h2 @ w_ff1^T + b_ff1)         (1024 blocks)
  gemm_bt<2><<<dim3(FFDIM/128, MTOK/128), 256, 0, stream>>>(H2, Wff1, bff1, FF1, MTOK, FFDIM, DMODEL);
  // 7) FF2 split-K=4 -> bf16 partials           (1024 blocks, 4/CU)
  gemm_sk128<<<dim3(DMODEL/128, MTOK/128, 4), 256, 0, stream>>>(FF1, Wff2, FP0, FP1, FP2, FP3, MTOK, DMODEL, FFDIM, FFDIM/4);
  // 8) out = sum(partials) + b_ff2 + x2
  combine_ff2_kernel<<<MTOK, 256, 0, stream>>>(FP0, FP1, FP2, FP3, bff2, X2f, out);
}

// Round 8
// 367.204 us; speedup vs baseline: 1.0744x; 1.0489x over previous
//
#include <hip/hip_runtime.h>
#include <stdint.h>

#define SEQ    2048
#define NB     2
#define DMODEL 1024
#define NHEAD  16
#define HDIM   64
#define FFDIM  4096
#define WIN    128
#define MTOK   (NB*SEQ)   // 4096 tokens

typedef short short8 __attribute__((ext_vector_type(8)));  // 8 bf16 (4 VGPRs)
typedef float f32x4  __attribute__((ext_vector_type(4)));

__device__ __forceinline__ float bf2f(uint16_t h){ return __uint_as_float(((uint32_t)h) << 16); }
__device__ __forceinline__ uint16_t f2bf(float f){           // RNE f32->bf16
  uint32_t u = __float_as_uint(f);
  u += 0x7fffu + ((u >> 16) & 1u);
  return (uint16_t)(u >> 16);
}

// tanh-form GELU, branch-free; max |delta| vs exact erf-GELU ~3e-3.
__device__ __forceinline__ float gelu_f(float v){
  float u = 0.7978845608028654f * v * (1.0f + 0.044715f * v * v);
  u = fminf(fmaxf(u, -10.0f), 10.0f);
  const float e = __expf(2.0f * u);
  const float th = (e - 1.0f) / (e + 1.0f);
  return 0.5f * v * (1.0f + th);
}

__device__ __forceinline__ void gl_lds16(const void* g, void* l) {
  __builtin_amdgcn_global_load_lds((const __attribute__((address_space(1))) void*)g,
                                   (__attribute__((address_space(3))) void*)l, 16, 0, 0);
}

// ---------- fused fp32->bf16 weight convert (wqkv|wout|wff1|wff2) ----------
__global__ __launch_bounds__(256) void cvt4_kernel(
    const float* __restrict__ s0, const float* __restrict__ s1,
    const float* __restrict__ s2, const float* __restrict__ s3,
    uint16_t* __restrict__ d0, uint16_t* __restrict__ d1,
    uint16_t* __restrict__ d2, uint16_t* __restrict__ d3)
{
  size_t i = (size_t)blockIdx.x * 256 + threadIdx.x;   // float4 index; 3M total
  const float* s; uint16_t* d; size_t off;
  if      (i <  768*1024) { s = s0; d = d0; off = i; }
  else if (i < 1024*1024) { s = s1; d = d1; off = i -  768*1024; }
  else if (i < 2048*1024) { s = s2; d = d2; off = i - 1024*1024; }
  else                    { s = s3; d = d3; off = i - 2048*1024; }
  const float4 v = ((const float4*)s)[off];
  uint2 o;
  o.x = (uint32_t)f2bf(v.x) | ((uint32_t)f2bf(v.y) << 16);
  o.y = (uint32_t)f2bf(v.z) | ((uint32_t)f2bf(v.w) << 16);
  ((uint2*)d)[off] = o;
}

// -------- LayerNorm: fp32 in -> bf16 out; one row (1024) per block ---------
__global__ __launch_bounds__(256) void ln_kernel(const float* __restrict__ x,
                                                 const float* __restrict__ g,
                                                 const float* __restrict__ b,
                                                 uint16_t* __restrict__ y)
{
  const int row = blockIdx.x;
  const int t = threadIdx.x;
  const float4 v = ((const float4*)(x + (size_t)row * DMODEL))[t];
  float s1 = v.x + v.y + v.z + v.w;
  float s2 = v.x*v.x + v.y*v.y + v.z*v.z + v.w*v.w;
  #pragma unroll
  for (int off = 32; off; off >>= 1) { s1 += __shfl_xor(s1, off, 64); s2 += __shfl_xor(s2, off, 64); }
  __shared__ float red[8];
  const int w = t >> 6;
  if ((t & 63) == 0) { red[w] = s1; red[4+w] = s2; }
  __syncthreads();
  s1 = red[0]+red[1]+red[2]+red[3];
  s2 = red[4]+red[5]+red[6]+red[7];
  const float mu = s1 * (1.0f/DMODEL);
  const float var = s2 * (1.0f/DMODEL) - mu*mu;
  const float rs = rsqrtf(var + 1e-5f);
  const float4 gv = ((const float4*)g)[t];
  const float4 bv = ((const float4*)b)[t];
  uint2 o;
  o.x = (uint32_t)f2bf((v.x-mu)*rs*gv.x + bv.x) | ((uint32_t)f2bf((v.y-mu)*rs*gv.y + bv.y) << 16);
  o.y = (uint32_t)f2bf((v.z-mu)*rs*gv.z + bv.z) | ((uint32_t)f2bf((v.w-mu)*rs*gv.w + bv.w) << 16);
  ((uint2*)(y + (size_t)row * DMODEL))[t] = o;
}

// ======================= BK=64 GEMM building blocks ========================
// LDS tile row = 64 bf16 = 128 B = 8 x 16B slots. Logical k-group g (g*8..g*8+7)
// of row r lives at physical slot p = g ^ (r&7) (XOR swizzle). Staging fetches
// global group (t&7)^((t>>3)&7) so lane->LDS stays contiguous for global_load_lds;
// fragment readers land 2 lanes/bank (free, m136). Half the barriers of BK=32.

// ---------- GEMM 128x128, BK=64: C = A @ Bm^T (+epilogue) ------------------
// EPI: 0 none (bf16 C), 2 +bias then GELU (bf16 C)
template<int EPI>
__global__ __launch_bounds__(256) void gemm_bt(
    const uint16_t* __restrict__ A, const uint16_t* __restrict__ Bm,
    const float* __restrict__ bias, uint16_t* __restrict__ C,
    int M, int N, int K)
{
  __shared__ __align__(16) uint16_t As[128*64];   // 16 KB
  __shared__ __align__(16) uint16_t Bs[128*64];   // 16 KB
  const int t = threadIdx.x;
  const int l = t & 63;
  const int w = t >> 6;
  const int row0 = blockIdx.y * 128;
  const int col0 = blockIdx.x * 128;
  const int wm = (w >> 1) * 64, wn = (w & 1) * 64;

  f32x4 acc[4][4];
  #pragma unroll
  for (int i = 0; i < 4; ++i)
    #pragma unroll
    for (int j = 0; j < 4; ++j)
      #pragma unroll
      for (int e = 0; e < 4; ++e) acc[i][j][e] = 0.0f;

  // staging: thread t covers (row = c*32 + (t>>3), phys slot = t&7) per chunk c
  const int sr8 = t >> 3;                 // 0..31
  const int sg  = (t & 7) ^ (sr8 & 7);    // global k-group fetched (chunk-invariant)
  const uint16_t* aG = A  + (size_t)(row0 + sr8) * K + sg * 8;
  const uint16_t* bG = Bm + (size_t)(col0 + sr8) * K + sg * 8;
  char* aL = (char*)As + t * 16;
  char* bL = (char*)Bs + t * 16;
  const int mrow = l & 15;
  const int kq = l >> 4;

  for (int k0 = 0; k0 < K; k0 += 64) {
    #pragma unroll
    for (int c = 0; c < 4; ++c) {
      gl_lds16(aG + k0 + (size_t)(c*32) * K, aL + c*4096);
      gl_lds16(bG + k0 + (size_t)(c*32) * K, bL + c*4096);
    }
    __syncthreads();
    #pragma unroll
    for (int ks = 0; ks < 2; ++ks) {
      const int pa = ((ks*4 + kq) ^ (mrow & 7)) * 16;
      short8 af[4], bfr[4];
      #pragma unroll
      for (int mi = 0; mi < 4; ++mi)
        af[mi] = *(const short8*)((const char*)As + (wm + mi*16 + mrow) * 128 + pa);
      #pragma unroll
      for (int ni = 0; ni < 4; ++ni)
        bfr[ni] = *(const short8*)((const char*)Bs + (wn + ni*16 + mrow) * 128 + pa);
      #pragma unroll
      for (int mi = 0; mi < 4; ++mi)
        #pragma unroll
        for (int ni = 0; ni < 4; ++ni)
          acc[mi][ni] = __builtin_amdgcn_mfma_f32_16x16x32_bf16(af[mi], bfr[ni], acc[mi][ni], 0, 0, 0);
    }
    __syncthreads();
  }

  const int crow = (l >> 4) * 4;   // C/D: col = lane&15, row = (lane>>4)*4 + reg
  float bv[4];
  #pragma unroll
  for (int ni = 0; ni < 4; ++ni)
    bv[ni] = (EPI != 0) ? bias[col0 + wn + ni*16 + mrow] : 0.0f;
  #pragma unroll
  for (int mi = 0; mi < 4; ++mi) {
    #pragma unroll
    for (int r = 0; r < 4; ++r) {
      const int row = row0 + wm + mi*16 + crow + r;
      #pragma unroll
      for (int ni = 0; ni < 4; ++ni) {
        const int col = col0 + wn + ni*16 + mrow;
        float v = acc[mi][ni][r] + bv[ni];
        if (EPI == 2) v = gelu_f(v);
        C[(size_t)row * N + col] = f2bf(v);
      }
    }
  }
}

// ------ split-K GEMM, 128x64 tile, BK=64: fp32 partial (out-proj) ----------
__global__ __launch_bounds__(256) void gemm_sk64(
    const uint16_t* __restrict__ A, const uint16_t* __restrict__ Bm,
    float* __restrict__ P0, float* __restrict__ P1,
    int M, int N, int K, int KS)
{
  __shared__ __align__(16) uint16_t As[128*64];   // 16 KB
  __shared__ __align__(16) uint16_t Bs[64*64];    //  8 KB
  const int t = threadIdx.x;
  const int l = t & 63;
  const int w = t >> 6;
  const int row0 = blockIdx.y * 128;
  const int col0 = blockIdx.x * 64;
  const int kbase = blockIdx.z * KS;
  float* P = blockIdx.z ? P1 : P0;
  const int wm = (w >> 1) * 64, wn = (w & 1) * 32;

  f32x4 acc[4][2];
  #pragma unroll
  for (int i = 0; i < 4; ++i)
    #pragma unroll
    for (int j = 0; j < 2; ++j)
      #pragma unroll
      for (int e = 0; e < 4; ++e) acc[i][j][e] = 0.0f;

  const int sr8 = t >> 3;
  const int sg  = (t & 7) ^ (sr8 & 7);
  const uint16_t* aG = A  + (size_t)(row0 + sr8) * K + kbase + sg * 8;
  const uint16_t* bG = Bm + (size_t)(col0 + sr8) * K + kbase + sg * 8;
  char* aL = (char*)As + t * 16;
  char* bL = (char*)Bs + t * 16;
  const int mrow = l & 15;
  const int kq = l >> 4;

  for (int k0 = 0; k0 < KS; k0 += 64) {
    #pragma unroll
    for (int c = 0; c < 4; ++c)
      gl_lds16(aG + k0 + (size_t)(c*32) * K, aL + c*4096);
    #pragma unroll
    for (int c = 0; c < 2; ++c)
      gl_lds16(bG + k0 + (size_t)(c*32) * K, bL + c*4096);
    __syncthreads();
    #pragma unroll
    for (int ks = 0; ks < 2; ++ks) {
      const int pa = ((ks*4 + kq) ^ (mrow & 7)) * 16;
      short8 af[4], bfr[2];
      #pragma unroll
      for (int mi = 0; mi < 4; ++mi)
        af[mi] = *(const short8*)((const char*)As + (wm + mi*16 + mrow) * 128 + pa);
      #pragma unroll
      for (int ni = 0; ni < 2; ++ni)
        bfr[ni] = *(const short8*)((const char*)Bs + (wn + ni*16 + mrow) * 128 + pa);
      #pragma unroll
      for (int mi = 0; mi < 4; ++mi)
        #pragma unroll
        for (int ni = 0; ni < 2; ++ni)
          acc[mi][ni] = __builtin_amdgcn_mfma_f32_16x16x32_bf16(af[mi], bfr[ni], acc[mi][ni], 0, 0, 0);
    }
    __syncthreads();
  }

  const int crow = (l >> 4) * 4;
  #pragma unroll
  for (int mi = 0; mi < 4; ++mi)
    #pragma unroll
    for (int r = 0; r < 4; ++r) {
      const int row = row0 + wm + mi*16 + crow + r;
      #pragma unroll
      for (int ni = 0; ni < 2; ++ni)
        P[(size_t)row * N + col0 + wn + ni*16 + mrow] = acc[mi][ni][r];
    }
}

// ------ split-K GEMM, 128x128 tile, BK=64: bf16 partial (FF2) --------------
__global__ __launch_bounds__(256) void gemm_sk128(
    const uint16_t* __restrict__ A, const uint16_t* __restrict__ Bm,
    uint16_t* __restrict__ P0, uint16_t* __restrict__ P1,
    uint16_t* __restrict__ P2, uint16_t* __restrict__ P3,
    int M, int N, int K, int KS)
{
  __shared__ __align__(16) uint16_t As[128*64];
  __shared__ __align__(16) uint16_t Bs[128*64];
  const int t = threadIdx.x;
  const int l = t & 63;
  const int w = t >> 6;
  const int row0 = blockIdx.y * 128;
  const int col0 = blockIdx.x * 128;
  const int z = blockIdx.z;
  const int kbase = z * KS;
  uint16_t* P = (z < 2) ? (z ? P1 : P0) : (z == 2 ? P2 : P3);
  const int wm = (w >> 1) * 64, wn = (w & 1) * 64;

  f32x4 acc[4][4];
  #pragma unroll
  for (int i = 0; i < 4; ++i)
    #pragma unroll
    for (int j = 0; j < 4; ++j)
      #pragma unroll
      for (int e = 0; e < 4; ++e) acc[i][j][e] = 0.0f;

  const int sr8 = t >> 3;
  const int sg  = (t & 7) ^ (sr8 & 7);
  const uint16_t* aG = A  + (size_t)(row0 + sr8) * K + kbase + sg * 8;
  const uint16_t* bG = Bm + (size_t)(col0 + sr8) * K + kbase + sg * 8;
  char* aL = (char*)As + t * 16;
  char* bL = (char*)Bs + t * 16;
  const int mrow = l & 15;
  const int kq = l >> 4;

  for (int k0 = 0; k0 < KS; k0 += 64) {
    #pragma unroll
    for (int c = 0; c < 4; ++c) {
      gl_lds16(aG + k0 + (size_t)(c*32) * K, aL + c*4096);
      gl_lds16(bG + k0 + (size_t)(c*32) * K, bL + c*4096);
    }
    __syncthreads();
    #pragma unroll
    for (int ks = 0; ks < 2; ++ks) {
      const int pa = ((ks*4 + kq) ^ (mrow & 7)) * 16;
      short8 af[4], bfr[4];
      #pragma unroll
      for (int mi = 0; mi < 4; ++mi)
        af[mi] = *(const short8*)((const char*)As + (wm + mi*16 + mrow) * 128 + pa);
      #pragma unroll
      for (int ni = 0; ni < 4; ++ni)
        bfr[ni] = *(const short8*)((const char*)Bs + (wn + ni*16 + mrow) * 128 + pa);
      #pragma unroll
      for (int mi = 0; mi < 4; ++mi)
        #pragma unroll
        for (int ni = 0; ni < 4; ++ni)
          acc[mi][ni] = __builtin_amdgcn_mfma_f32_16x16x32_bf16(af[mi], bfr[ni], acc[mi][ni], 0, 0, 0);
    }
    __syncthreads();
  }

  const int crow = (l >> 4) * 4;
  #pragma unroll
  for (int mi = 0; mi < 4; ++mi)
    #pragma unroll
    for (int r = 0; r < 4; ++r) {
      const int row = row0 + wm + mi*16 + crow + r;
      #pragma unroll
      for (int ni = 0; ni < 4; ++ni)
        P[(size_t)row * N + col0 + wn + ni*16 + mrow] = f2bf(acc[mi][ni][r]);
    }
}

// ---- combine out-proj partials + bias + residual, then LN2, in one pass ---
__global__ __launch_bounds__(256) void combine_ln2_kernel(
    const float* __restrict__ p0, const float* __restrict__ p1,
    const float* __restrict__ x,  const float* __restrict__ bout,
    const float* __restrict__ g,  const float* __restrict__ b,
    float* __restrict__ X2f, uint16_t* __restrict__ H2)
{
  const int row = blockIdx.x;
  const int t = threadIdx.x;
  const size_t off = (size_t)row * (DMODEL/4) + t;
  const float4 a0 = ((const float4*)p0)[off];
  const float4 a1 = ((const float4*)p1)[off];
  const float4 xv = ((const float4*)x)[off];
  const float4 bo = ((const float4*)bout)[t];
  float4 v;
  v.x = a0.x + a1.x + xv.x + bo.x;
  v.y = a0.y + a1.y + xv.y + bo.y;
  v.z = a0.z + a1.z + xv.z + bo.z;
  v.w = a0.w + a1.w + xv.w + bo.w;
  ((float4*)X2f)[off] = v;
  float s1 = v.x + v.y + v.z + v.w;
  float s2 = v.x*v.x + v.y*v.y + v.z*v.z + v.w*v.w;
  #pragma unroll
  for (int o = 32; o; o >>= 1) { s1 += __shfl_xor(s1, o, 64); s2 += __shfl_xor(s2, o, 64); }
  __shared__ float red[8];
  const int w = t >> 6;
  if ((t & 63) == 0) { red[w] = s1; red[4+w] = s2; }
  __syncthreads();
  s1 = red[0]+red[1]+red[2]+red[3];
  s2 = red[4]+red[5]+red[6]+red[7];
  const float mu = s1 * (1.0f/DMODEL);
  const float var = s2 * (1.0f/DMODEL) - mu*mu;
  const float rs = rsqrtf(var + 1e-5f);
  const float4 gv = ((const float4*)g)[t];
  const float4 bv = ((const float4*)b)[t];
  uint2 o;
  o.x = (uint32_t)f2bf((v.x-mu)*rs*gv.x + bv.x) | ((uint32_t)f2bf((v.y-mu)*rs*gv.y + bv.y) << 16);
  o.y = (uint32_t)f2bf((v.z-mu)*rs*gv.z + bv.z) | ((uint32_t)f2bf((v.w-mu)*rs*gv.w + bv.w) << 16);
  ((uint2*)(H2 + (size_t)row * DMODEL))[t] = o;
}

// ---------- combine FF2 bf16 partials + bias + residual -> fp32 out --------
__global__ __launch_bounds__(256) void combine_ff2_kernel(
    const uint16_t* __restrict__ p0, const uint16_t* __restrict__ p1,
    const uint16_t* __restrict__ p2, const uint16_t* __restrict__ p3,
    const float* __restrict__ bff2, const float* __restrict__ X2f,
    float* __restrict__ out)
{
  const int row = blockIdx.x;
  const int t = threadIdx.x;
  const size_t eoff = (size_t)row * DMODEL + t * 4;
  const uint2 u0 = *(const uint2*)(p0 + eoff);
  const uint2 u1 = *(const uint2*)(p1 + eoff);
  const uint2 u2 = *(const uint2*)(p2 + eoff);
  const uint2 u3 = *(const uint2*)(p3 + eoff);
  const float4 xv = ((const float4*)X2f)[(size_t)row * (DMODEL/4) + t];
  const float4 bo = ((const float4*)bff2)[t];
  float4 v;
  v.x = bf2f((uint16_t)(u0.x & 0xffff)) + bf2f((uint16_t)(u1.x & 0xffff))
      + bf2f((uint16_t)(u2.x & 0xffff)) + bf2f((uint16_t)(u3.x & 0xffff)) + bo.x + xv.x;
  v.y = bf2f((uint16_t)(u0.x >> 16)) + bf2f((uint16_t)(u1.x >> 16))
      + bf2f((uint16_t)(u2.x >> 16)) + bf2f((uint16_t)(u3.x >> 16)) + bo.y + xv.y;
  v.z = bf2f((uint16_t)(u0.y & 0xffff)) + bf2f((uint16_t)(u1.y & 0xffff))
      + bf2f((uint16_t)(u2.y & 0xffff)) + bf2f((uint16_t)(u3.y & 0xffff)) + bo.z + xv.z;
  v.w = bf2f((uint16_t)(u0.y >> 16)) + bf2f((uint16_t)(u1.y >> 16))
      + bf2f((uint16_t)(u2.y >> 16)) + bf2f((uint16_t)(u3.y >> 16)) + bo.w + xv.w;
  ((float4*)out)[(size_t)row * (DMODEL/4) + t] = v;
}

// --------------------- local-window attention (MFMA) -----------------------
#define TQ    32
#define NKT   18
#define NKP   (NKT*16)   // 288 key slots
#define KSTR  72         // Qs/KV row stride (bf16)
#define PSTR  296        // Ps/Vt row stride (bf16)

__global__ __launch_bounds__(256) void attn_kernel(const uint16_t* __restrict__ qkv,
                                                   uint16_t* __restrict__ out)
{
  __shared__ uint16_t Qs[TQ * KSTR];
  __shared__ uint16_t Ps[TQ * PSTR];
  __shared__ uint16_t KV[NKP * KSTR];
  const int t = threadIdx.x, l = t & 63, w = t >> 6;
  const int b = blockIdx.z, hh = blockIdx.y, q0 = blockIdx.x * TQ;
  const int k0 = (q0 - WIN > 0) ? (q0 - WIN) : 0;
  const int kend_ = q0 + TQ + WIN;
  const int kend = (kend_ < SEQ) ? kend_ : SEQ;
  const int nk = kend - k0;

  {
    const int r = t >> 3, gg = t & 7;
    const uint4 qv = *(const uint4*)(qkv + (size_t)(b*SEQ + q0 + r) * 3072 + hh*64 + gg*8);
    *(uint4*)((char*)Qs + r*(KSTR*2) + gg*16) = qv;
    for (int j = r; j < NKP; j += 32) {
      uint4 kv; kv.x = 0; kv.y = 0; kv.z = 0; kv.w = 0;
      if (j < nk)
        kv = *(const uint4*)(qkv + (size_t)(b*SEQ + k0 + j) * 3072 + 1024 + hh*64 + gg*8);
      *(uint4*)((char*)KV + j*(KSTR*2) + gg*16) = kv;
    }
  }
  __syncthreads();

  if (w < 2) {
    const int rb = w * 16;
    const int mrow = l & 15, q4 = l >> 4;
    const short8 aq0 = *(const short8*)((const char*)Qs + (rb + mrow)*(KSTR*2) + q4*16);
    const short8 aq1 = *(const short8*)((const char*)Qs + (rb + mrow)*(KSTR*2) + 64 + q4*16);
    f32x4 cacc[NKT];
    #pragma unroll
    for (int ct = 0; ct < NKT; ++ct) {
      f32x4 c; c[0]=0.f; c[1]=0.f; c[2]=0.f; c[3]=0.f;
      const short8 b0 = *(const short8*)((const char*)KV + (ct*16 + mrow)*(KSTR*2) + q4*16);
      const short8 b1 = *(const short8*)((const char*)KV + (ct*16 + mrow)*(KSTR*2) + 64 + q4*16);
      c = __builtin_amdgcn_mfma_f32_16x16x32_bf16(aq0, b0, c, 0, 0, 0);
      c = __builtin_amdgcn_mfma_f32_16x16x32_bf16(aq1, b1, c, 0, 0, 0);
      cacc[ct] = c;
    }
    #pragma unroll
    for (int r = 0; r < 4; ++r) {
      const int iq = q0 + rb + q4*4 + r;
      float m = -1e30f;
      #pragma unroll
      for (int ct = 0; ct < NKT; ++ct) {
        const int jj = ct*16 + mrow;
        const int j = k0 + jj;
        const bool ok = (jj < nk) && (j >= iq - WIN) && (j <= iq + WIN);
        const float s = ok ? cacc[ct][r] * 0.125f : -1e30f;
        cacc[ct][r] = s;
        m = fmaxf(m, s);
      }
      m = fmaxf(m, __shfl_xor(m, 1, 64));
      m = fmaxf(m, __shfl_xor(m, 2, 64));
      m = fmaxf(m, __shfl_xor(m, 4, 64));
      m = fmaxf(m, __shfl_xor(m, 8, 64));
      float s = 0.f;
      #pragma unroll
      for (int ct = 0; ct < NKT; ++ct) {
        const float e = __expf(cacc[ct][r] - m);
        cacc[ct][r] = e;
        s += e;
      }
      s += __shfl_xor(s, 1, 64);
      s += __shfl_xor(s, 2, 64);
      s += __shfl_xor(s, 4, 64);
      s += __shfl_xor(s, 8, 64);
      const float rinv = 1.0f / s;
      #pragma unroll
      for (int ct = 0; ct < NKT; ++ct)
        Ps[(rb + q4*4 + r) * PSTR + ct*16 + mrow] = f2bf(cacc[ct][r] * rinv);
    }
  }
  __syncthreads();

  {
    uint16_t* Vt = KV;
    const int gg = t & 7;
    for (int j = t >> 3; j < NKP; j += 32) {
      if (j < nk) {
        const uint4 v = *(const uint4*)(qkv + (size_t)(b*SEQ + k0 + j) * 3072 + 2048 + hh*64 + gg*8);
        uint16_t e[8] = { (uint16_t)(v.x & 0xffff), (uint16_t)(v.x >> 16),
                          (uint16_t)(v.y & 0xffff), (uint16_t)(v.y >> 16),
                          (uint16_t)(v.z & 0xffff), (uint16_t)(v.z >> 16),
                          (uint16_t)(v.w & 0xffff), (uint16_t)(v.w >> 16) };
        #pragma unroll
        for (int dd = 0; dd < 8; ++dd) Vt[(gg*8 + dd) * PSTR + j] = e[dd];
      } else {
        #pragma unroll
        for (int dd = 0; dd < 8; ++dd) Vt[(gg*8 + dd) * PSTR + j] = 0;
      }
    }
  }
  __syncthreads();

  {
    const uint16_t* Vt = KV;
    const int mrow = l & 15, q4 = l >> 4;
    const int rt = w & 1, dt0 = (w >> 1) * 2;
    f32x4 o0, o1;
    #pragma unroll
    for (int e = 0; e < 4; ++e) { o0[e] = 0.f; o1[e] = 0.f; }
    #pragma unroll
    for (int ks = 0; ks < 9; ++ks) {
      const short8 a  = *(const short8*)((const char*)Ps + (rt*16 + mrow)*(PSTR*2) + ks*64 + q4*16);
      const short8 v0 = *(const short8*)((const char*)Vt + ((dt0  )*16 + mrow)*(PSTR*2) + ks*64 + q4*16);
      const short8 v1 = *(const short8*)((const char*)Vt + ((dt0+1)*16 + mrow)*(PSTR*2) + ks*64 + q4*16);
      o0 = __builtin_amdgcn_mfma_f32_16x16x32_bf16(a, v0, o0, 0, 0, 0);
      o1 = __builtin_amdgcn_mfma_f32_16x16x32_bf16(a, v1, o1, 0, 0, 0);
    }
    #pragma unroll
    for (int r = 0; r < 4; ++r) {
      const int iq = q0 + rt*16 + q4*4 + r;
      const size_t rowoff = (size_t)(b*SEQ + iq) * DMODEL + hh*64;
      out[rowoff + (dt0  )*16 + mrow] = f2bf(o0[r]);
      out[rowoff + (dt0+1)*16 + mrow] = f2bf(o1[r]);
    }
  }
}

// --------------------------------- launch ----------------------------------
extern "C" void kernel_launch(void* const* d_in, const int* in_sizes, int n_in,
                              void* d_out, int out_size, void* d_ws, size_t ws_size,
                              hipStream_t stream)
{
  const float* x    = (const float*)d_in[0];
  const float* ln1g = (const float*)d_in[1];
  const float* ln1b = (const float*)d_in[2];
  const float* wqkv = (const float*)d_in[3];
  const float* wout = (const float*)d_in[4];
  const float* bout = (const float*)d_in[5];
  const float* ln2g = (const float*)d_in[6];
  const float* ln2b = (const float*)d_in[7];
  const float* wff1 = (const float*)d_in[8];
  const float* bff1 = (const float*)d_in[9];
  const float* wff2 = (const float*)d_in[10];
  const float* bff2 = (const float*)d_in[11];
  float* out = (float*)d_out;

  char* ws = (char*)d_ws;
  const size_t MB = (size_t)1 << 20;
  uint16_t* Wqkv = (uint16_t*)(ws);            //  0-6   (dead after qkv gemm)
  uint16_t* Wout = (uint16_t*)(ws +  6*MB);    //  6-8   (dead after out-proj)
  uint16_t* Wff1 = (uint16_t*)(ws +  8*MB);    //  8-16  (dead after ff1)
  uint16_t* Wff2 = (uint16_t*)(ws + 16*MB);    // 16-24  (live until ff2)
  uint16_t* QKV  = (uint16_t*)(ws + 24*MB);    // 24-48  (dead after attn)
  uint16_t* H1   = (uint16_t*)(ws + 48*MB);    // 48-56  h1 -> attn_out
  uint16_t* AT   = H1;
  float*    X2f  = (float*)   (ws + 56*MB);    // 56-72  fp32 (live to end)
  uint16_t* H2   = (uint16_t*)(ws + 72*MB);    // 72-80  (dead after ff1)
  float*    OP0  = (float*)   (ws + 24*MB);    // 24-40  (ex-QKV)
  float*    OP1  = (float*)   (ws + 80*MB);    // 80-96
  uint16_t* FF1  = (uint16_t*)(ws + 24*MB);    // 24-56  (after combine)
  uint16_t* FP0  = (uint16_t*)(ws);            //  0-8
  uint16_t* FP1  = (uint16_t*)(ws +  8*MB);    //  8-16
  uint16_t* FP2  = (uint16_t*)(ws + 72*MB);    // 72-80
  uint16_t* FP3  = (uint16_t*)(ws + 80*MB);    // 80-88
  // high-water: 96 MB (ws proven >= 97 MB by round-3 diagnostic)

  // 0) weights fp32 -> bf16
  cvt4_kernel<<<12288, 256, 0, stream>>>(wqkv, wout, wff1, wff2, Wqkv, Wout, Wff1, Wff2);
  // 1) h1 = LN1(x)
  ln_kernel<<<MTOK, 256, 0, stream>>>(x, ln1g, ln1b, H1);
  // 2) qkv = h1 @ w_qkv^T                       (768 blocks)
  gemm_bt<0><<<dim3(3072/128, MTOK/128), 256, 0, stream>>>(H1, Wqkv, nullptr, QKV, MTOK, 3072, DMODEL);
  // 3) attn_out = local_attention(qkv)
  attn_kernel<<<dim3(SEQ/TQ, NHEAD, NB), 256, 0, stream>>>(QKV, AT);
  // 4) out-proj split-K=2 -> fp32 partials      (1024 blocks, 4/CU)
  gemm_sk64<<<dim3(DMODEL/64, MTOK/128, 2), 256, 0, stream>>>(AT, Wout, OP0, OP1, MTOK, DMODEL, DMODEL, DMODEL/2);
  // 5) x2 = p0+p1+b_out+x; h2 = LN2(x2)         (fused)
  combine_ln2_kernel<<<MTOK, 256, 0, stream>>>(OP0, OP1, x, bout, ln2g, ln2b, X2f, H2);
  // 6) ff1 = gelu(h2 @ w_ff1^T + b_ff1)         (1024 blocks)
  gemm_bt<2><<<dim3(FFDIM/128, MTOK/128), 256, 0, stream>>>(H2, Wff1, bff1, FF1, MTOK, FFDIM, DMODEL);
  // 7) FF2 split-K=4 -> bf16 partials           (1024 blocks, 4/CU)
  gemm_sk128<<<dim3(DMODEL/128, MTOK/128, 4), 256, 0, stream>>>(FF1, Wff2, FP0, FP1, FP2, FP3, MTOK, DMODEL, FFDIM, FFDIM/4);
  // 8) out = sum(partials) + b_ff2 + x2
  combine_ff2_kernel<<<MTOK, 256, 0, stream>>>(FP0, FP1, FP2, FP3, bff2, X2f, out);
}

// Round 9
// 349.847 us; speedup vs baseline: 1.1277x; 1.0496x over previous
//
#include <hip/hip_runtime.h>
#include <stdint.h>

#define SEQ    2048
#define NB     2
#define DMODEL 1024
#define NHEAD  16
#define HDIM   64
#define FFDIM  4096
#define WIN    128
#define MTOK   (NB*SEQ)   // 4096 tokens

typedef short short8 __attribute__((ext_vector_type(8)));  // 8 bf16 (4 VGPRs)
typedef float f32x4  __attribute__((ext_vector_type(4)));

__device__ __forceinline__ float bf2f(uint16_t h){ return __uint_as_float(((uint32_t)h) << 16); }
__device__ __forceinline__ uint16_t f2bf(float f){           // RNE f32->bf16
  uint32_t u = __float_as_uint(f);
  u += 0x7fffu + ((u >> 16) & 1u);
  return (uint16_t)(u >> 16);
}

// tanh-form GELU, branch-free; max |delta| vs exact erf-GELU ~3e-3.
__device__ __forceinline__ float gelu_f(float v){
  float u = 0.7978845608028654f * v * (1.0f + 0.044715f * v * v);
  u = fminf(fmaxf(u, -10.0f), 10.0f);
  const float e = __expf(2.0f * u);
  const float th = (e - 1.0f) / (e + 1.0f);
  return 0.5f * v * (1.0f + th);
}

__device__ __forceinline__ void gl_lds16(const void* g, void* l) {
  __builtin_amdgcn_global_load_lds((const __attribute__((address_space(1))) void*)g,
                                   (__attribute__((address_space(3))) void*)l, 16, 0, 0);
}

// ---- fused: weights fp32->bf16 (blocks 0..12287) + LN1 (blocks 12288..16383)
__global__ __launch_bounds__(256) void cvtln_kernel(
    const float* __restrict__ s0, const float* __restrict__ s1,
    const float* __restrict__ s2, const float* __restrict__ s3,
    uint16_t* __restrict__ d0, uint16_t* __restrict__ d1,
    uint16_t* __restrict__ d2, uint16_t* __restrict__ d3,
    const float* __restrict__ x, const float* __restrict__ g,
    const float* __restrict__ b, uint16_t* __restrict__ y)
{
  __shared__ float red[8];
  const int t = threadIdx.x;
  if (blockIdx.x < 12288) {
    size_t i = (size_t)blockIdx.x * 256 + t;   // float4 index; 3,145,728 total
    const float* s; uint16_t* d; size_t off;
    if      (i <  768*1024) { s = s0; d = d0; off = i; }
    else if (i < 1024*1024) { s = s1; d = d1; off = i -  768*1024; }
    else if (i < 2048*1024) { s = s2; d = d2; off = i - 1024*1024; }
    else                    { s = s3; d = d3; off = i - 2048*1024; }
    const float4 v = ((const float4*)s)[off];
    uint2 o;
    o.x = (uint32_t)f2bf(v.x) | ((uint32_t)f2bf(v.y) << 16);
    o.y = (uint32_t)f2bf(v.z) | ((uint32_t)f2bf(v.w) << 16);
    ((uint2*)d)[off] = o;
  } else {
    const int row = blockIdx.x - 12288;
    const float4 v = ((const float4*)(x + (size_t)row * DMODEL))[t];
    float s1 = v.x + v.y + v.z + v.w;
    float s2 = v.x*v.x + v.y*v.y + v.z*v.z + v.w*v.w;
    #pragma unroll
    for (int off = 32; off; off >>= 1) { s1 += __shfl_xor(s1, off, 64); s2 += __shfl_xor(s2, off, 64); }
    const int w = t >> 6;
    if ((t & 63) == 0) { red[w] = s1; red[4+w] = s2; }
    __syncthreads();
    s1 = red[0]+red[1]+red[2]+red[3];
    s2 = red[4]+red[5]+red[6]+red[7];
    const float mu = s1 * (1.0f/DMODEL);
    const float var = s2 * (1.0f/DMODEL) - mu*mu;
    const float rs = rsqrtf(var + 1e-5f);
    const float4 gv = ((const float4*)g)[t];
    const float4 bv = ((const float4*)b)[t];
    uint2 o;
    o.x = (uint32_t)f2bf((v.x-mu)*rs*gv.x + bv.x) | ((uint32_t)f2bf((v.y-mu)*rs*gv.y + bv.y) << 16);
    o.y = (uint32_t)f2bf((v.z-mu)*rs*gv.z + bv.z) | ((uint32_t)f2bf((v.w-mu)*rs*gv.w + bv.w) << 16);
    ((uint2*)(y + (size_t)row * DMODEL))[t] = o;
  }
}

// -------- LayerNorm: fp32 in -> bf16 out; one row (1024) per block ---------
__global__ __launch_bounds__(256) void ln_kernel(const float* __restrict__ x,
                                                 const float* __restrict__ g,
                                                 const float* __restrict__ b,
                                                 uint16_t* __restrict__ y)
{
  const int row = blockIdx.x;
  const int t = threadIdx.x;
  const float4 v = ((const float4*)(x + (size_t)row * DMODEL))[t];
  float s1 = v.x + v.y + v.z + v.w;
  float s2 = v.x*v.x + v.y*v.y + v.z*v.z + v.w*v.w;
  #pragma unroll
  for (int off = 32; off; off >>= 1) { s1 += __shfl_xor(s1, off, 64); s2 += __shfl_xor(s2, off, 64); }
  __shared__ float red[8];
  const int w = t >> 6;
  if ((t & 63) == 0) { red[w] = s1; red[4+w] = s2; }
  __syncthreads();
  s1 = red[0]+red[1]+red[2]+red[3];
  s2 = red[4]+red[5]+red[6]+red[7];
  const float mu = s1 * (1.0f/DMODEL);
  const float var = s2 * (1.0f/DMODEL) - mu*mu;
  const float rs = rsqrtf(var + 1e-5f);
  const float4 gv = ((const float4*)g)[t];
  const float4 bv = ((const float4*)b)[t];
  uint2 o;
  o.x = (uint32_t)f2bf((v.x-mu)*rs*gv.x + bv.x) | ((uint32_t)f2bf((v.y-mu)*rs*gv.y + bv.y) << 16);
  o.y = (uint32_t)f2bf((v.z-mu)*rs*gv.z + bv.z) | ((uint32_t)f2bf((v.w-mu)*rs*gv.w + bv.w) << 16);
  ((uint2*)(y + (size_t)row * DMODEL))[t] = o;
}

// ======================= BK=64 GEMM building blocks ========================
// LDS row = 64 bf16 = 128 B = 8 x 16B slots; logical k-group g of row r at
// physical slot g^(r&7). Staging fetches global group (t&7)^((t>>3)&7) so the
// lane->LDS map stays contiguous for global_load_lds; readers conflict-free
// (verified: SQ_LDS_BANK_CONFLICT 4.2M -> 0 in round 8).

// ---------- GEMM 128x128, BK=64: C = A @ Bm^T (bf16 C; EPI2 = bias+GELU) ---
template<int EPI>
__global__ __launch_bounds__(256) void gemm_bt(
    const uint16_t* __restrict__ A, const uint16_t* __restrict__ Bm,
    const float* __restrict__ bias, uint16_t* __restrict__ C,
    int M, int N, int K)
{
  __shared__ __align__(16) uint16_t As[128*64];   // 16 KB
  __shared__ __align__(16) uint16_t Bs[128*64];   // 16 KB
  const int t = threadIdx.x;
  const int l = t & 63;
  const int w = t >> 6;
  const int row0 = blockIdx.y * 128;
  const int col0 = blockIdx.x * 128;
  const int wm = (w >> 1) * 64, wn = (w & 1) * 64;

  f32x4 acc[4][4];
  #pragma unroll
  for (int i = 0; i < 4; ++i)
    #pragma unroll
    for (int j = 0; j < 4; ++j)
      #pragma unroll
      for (int e = 0; e < 4; ++e) acc[i][j][e] = 0.0f;

  const int sr8 = t >> 3;
  const int sg  = (t & 7) ^ (sr8 & 7);
  const uint16_t* aG = A  + (size_t)(row0 + sr8) * K + sg * 8;
  const uint16_t* bG = Bm + (size_t)(col0 + sr8) * K + sg * 8;
  char* aL = (char*)As + t * 16;
  char* bL = (char*)Bs + t * 16;
  const int mrow = l & 15;
  const int kq = l >> 4;

  for (int k0 = 0; k0 < K; k0 += 64) {
    #pragma unroll
    for (int c = 0; c < 4; ++c) {
      gl_lds16(aG + k0 + (size_t)(c*32) * K, aL + c*4096);
      gl_lds16(bG + k0 + (size_t)(c*32) * K, bL + c*4096);
    }
    __syncthreads();
    #pragma unroll
    for (int ks = 0; ks < 2; ++ks) {
      const int pa = ((ks*4 + kq) ^ (mrow & 7)) * 16;
      short8 af[4], bfr[4];
      #pragma unroll
      for (int mi = 0; mi < 4; ++mi)
        af[mi] = *(const short8*)((const char*)As + (wm + mi*16 + mrow) * 128 + pa);
      #pragma unroll
      for (int ni = 0; ni < 4; ++ni)
        bfr[ni] = *(const short8*)((const char*)Bs + (wn + ni*16 + mrow) * 128 + pa);
      #pragma unroll
      for (int mi = 0; mi < 4; ++mi)
        #pragma unroll
        for (int ni = 0; ni < 4; ++ni)
          acc[mi][ni] = __builtin_amdgcn_mfma_f32_16x16x32_bf16(af[mi], bfr[ni], acc[mi][ni], 0, 0, 0);
    }
    __syncthreads();
  }

  const int crow = (l >> 4) * 4;   // C/D: col = lane&15, row = (lane>>4)*4 + reg
  float bv[4];
  #pragma unroll
  for (int ni = 0; ni < 4; ++ni)
    bv[ni] = (EPI != 0) ? bias[col0 + wn + ni*16 + mrow] : 0.0f;
  #pragma unroll
  for (int mi = 0; mi < 4; ++mi) {
    #pragma unroll
    for (int r = 0; r < 4; ++r) {
      const int row = row0 + wm + mi*16 + crow + r;
      #pragma unroll
      for (int ni = 0; ni < 4; ++ni) {
        const int col = col0 + wn + ni*16 + mrow;
        float v = acc[mi][ni][r] + bv[ni];
        if (EPI == 2) v = gelu_f(v);
        C[(size_t)row * N + col] = f2bf(v);
      }
    }
  }
}

// ---------- GEMM 128x64 tile, BK=64, bf16 out, no epilogue (QKV) -----------
// grid (N/64, M/128): 1536 blocks for QKV -> 6 blocks/CU.
__global__ __launch_bounds__(256) void gemm_qkv(
    const uint16_t* __restrict__ A, const uint16_t* __restrict__ Bm,
    uint16_t* __restrict__ C, int M, int N, int K)
{
  __shared__ __align__(16) uint16_t As[128*64];   // 16 KB
  __shared__ __align__(16) uint16_t Bs[64*64];    //  8 KB
  const int t = threadIdx.x;
  const int l = t & 63;
  const int w = t >> 6;
  const int row0 = blockIdx.y * 128;
  const int col0 = blockIdx.x * 64;
  const int wm = (w >> 1) * 64, wn = (w & 1) * 32;

  f32x4 acc[4][2];
  #pragma unroll
  for (int i = 0; i < 4; ++i)
    #pragma unroll
    for (int j = 0; j < 2; ++j)
      #pragma unroll
      for (int e = 0; e < 4; ++e) acc[i][j][e] = 0.0f;

  const int sr8 = t >> 3;
  const int sg  = (t & 7) ^ (sr8 & 7);
  const uint16_t* aG = A  + (size_t)(row0 + sr8) * K + sg * 8;
  const uint16_t* bG = Bm + (size_t)(col0 + sr8) * K + sg * 8;
  char* aL = (char*)As + t * 16;
  char* bL = (char*)Bs + t * 16;
  const int mrow = l & 15;
  const int kq = l >> 4;

  for (int k0 = 0; k0 < K; k0 += 64) {
    #pragma unroll
    for (int c = 0; c < 4; ++c)
      gl_lds16(aG + k0 + (size_t)(c*32) * K, aL + c*4096);
    #pragma unroll
    for (int c = 0; c < 2; ++c)
      gl_lds16(bG + k0 + (size_t)(c*32) * K, bL + c*4096);
    __syncthreads();
    #pragma unroll
    for (int ks = 0; ks < 2; ++ks) {
      const int pa = ((ks*4 + kq) ^ (mrow & 7)) * 16;
      short8 af[4], bfr[2];
      #pragma unroll
      for (int mi = 0; mi < 4; ++mi)
        af[mi] = *(const short8*)((const char*)As + (wm + mi*16 + mrow) * 128 + pa);
      #pragma unroll
      for (int ni = 0; ni < 2; ++ni)
        bfr[ni] = *(const short8*)((const char*)Bs + (wn + ni*16 + mrow) * 128 + pa);
      #pragma unroll
      for (int mi = 0; mi < 4; ++mi)
        #pragma unroll
        for (int ni = 0; ni < 2; ++ni)
          acc[mi][ni] = __builtin_amdgcn_mfma_f32_16x16x32_bf16(af[mi], bfr[ni], acc[mi][ni], 0, 0, 0);
    }
    __syncthreads();
  }

  const int crow = (l >> 4) * 4;
  #pragma unroll
  for (int mi = 0; mi < 4; ++mi)
    #pragma unroll
    for (int r = 0; r < 4; ++r) {
      const int row = row0 + wm + mi*16 + crow + r;
      #pragma unroll
      for (int ni = 0; ni < 2; ++ni)
        C[(size_t)row * N + col0 + wn + ni*16 + mrow] = f2bf(acc[mi][ni][r]);
    }
}

// ----- GEMM 64x64 tile, BK=64, full-K, fused bias + fp32 residual ----------
// grid (N/64, M/64) = 1024 blocks for N=1024 -> 4 blocks/CU. fp32 out.
__global__ __launch_bounds__(256) void gemm64(
    const uint16_t* __restrict__ A, const uint16_t* __restrict__ Bm,
    const float* __restrict__ bias, const float* __restrict__ res,
    float* __restrict__ out, int M, int N, int K)
{
  __shared__ __align__(16) uint16_t As[64*64];    // 8 KB
  __shared__ __align__(16) uint16_t Bs[64*64];    // 8 KB
  const int t = threadIdx.x;
  const int l = t & 63;
  const int w = t >> 6;
  const int row0 = blockIdx.y * 64;
  const int col0 = blockIdx.x * 64;
  const int wm = (w >> 1) * 32, wn = (w & 1) * 32;

  f32x4 acc[2][2];
  #pragma unroll
  for (int i = 0; i < 2; ++i)
    #pragma unroll
    for (int j = 0; j < 2; ++j)
      #pragma unroll
      for (int e = 0; e < 4; ++e) acc[i][j][e] = 0.0f;

  const int sr8 = t >> 3;
  const int sg  = (t & 7) ^ (sr8 & 7);
  const uint16_t* aG = A  + (size_t)(row0 + sr8) * K + sg * 8;
  const uint16_t* bG = Bm + (size_t)(col0 + sr8) * K + sg * 8;
  char* aL = (char*)As + t * 16;
  char* bL = (char*)Bs + t * 16;
  const int mrow = l & 15;
  const int kq = l >> 4;

  for (int k0 = 0; k0 < K; k0 += 64) {
    gl_lds16(aG + k0,                    aL);
    gl_lds16(aG + k0 + (size_t)32 * K,   aL + 4096);
    gl_lds16(bG + k0,                    bL);
    gl_lds16(bG + k0 + (size_t)32 * K,   bL + 4096);
    __syncthreads();
    #pragma unroll
    for (int ks = 0; ks < 2; ++ks) {
      const int pa = ((ks*4 + kq) ^ (mrow & 7)) * 16;
      short8 af[2], bfr[2];
      #pragma unroll
      for (int mi = 0; mi < 2; ++mi)
        af[mi] = *(const short8*)((const char*)As + (wm + mi*16 + mrow) * 128 + pa);
      #pragma unroll
      for (int ni = 0; ni < 2; ++ni)
        bfr[ni] = *(const short8*)((const char*)Bs + (wn + ni*16 + mrow) * 128 + pa);
      #pragma unroll
      for (int mi = 0; mi < 2; ++mi)
        #pragma unroll
        for (int ni = 0; ni < 2; ++ni)
          acc[mi][ni] = __builtin_amdgcn_mfma_f32_16x16x32_bf16(af[mi], bfr[ni], acc[mi][ni], 0, 0, 0);
    }
    __syncthreads();
  }

  const int crow = (l >> 4) * 4;
  float bv[2];
  #pragma unroll
  for (int ni = 0; ni < 2; ++ni)
    bv[ni] = bias[col0 + wn + ni*16 + mrow];
  #pragma unroll
  for (int mi = 0; mi < 2; ++mi)
    #pragma unroll
    for (int r = 0; r < 4; ++r) {
      const int row = row0 + wm + mi*16 + crow + r;
      #pragma unroll
      for (int ni = 0; ni < 2; ++ni) {
        const int col = col0 + wn + ni*16 + mrow;
        out[(size_t)row * N + col] = acc[mi][ni][r] + bv[ni] + res[(size_t)row * N + col];
      }
    }
}

// --------------------- local-window attention (MFMA) -----------------------
#define TQ    32
#define NKT   18
#define NKP   (NKT*16)   // 288 key slots
#define KSTR  72         // Qs/KV row stride (bf16)
#define PSTR  296        // Ps/Vt row stride (bf16)

__global__ __launch_bounds__(256) void attn_kernel(const uint16_t* __restrict__ qkv,
                                                   uint16_t* __restrict__ out)
{
  __shared__ uint16_t Qs[TQ * KSTR];
  __shared__ uint16_t Ps[TQ * PSTR];
  __shared__ uint16_t KV[NKP * KSTR];
  const int t = threadIdx.x, l = t & 63, w = t >> 6;
  const int b = blockIdx.z, hh = blockIdx.y, q0 = blockIdx.x * TQ;
  const int k0 = (q0 - WIN > 0) ? (q0 - WIN) : 0;
  const int kend_ = q0 + TQ + WIN;
  const int kend = (kend_ < SEQ) ? kend_ : SEQ;
  const int nk = kend - k0;

  {
    const int r = t >> 3, gg = t & 7;
    const uint4 qv = *(const uint4*)(qkv + (size_t)(b*SEQ + q0 + r) * 3072 + hh*64 + gg*8);
    *(uint4*)((char*)Qs + r*(KSTR*2) + gg*16) = qv;
    for (int j = r; j < NKP; j += 32) {
      uint4 kv; kv.x = 0; kv.y = 0; kv.z = 0; kv.w = 0;
      if (j < nk)
        kv = *(const uint4*)(qkv + (size_t)(b*SEQ + k0 + j) * 3072 + 1024 + hh*64 + gg*8);
      *(uint4*)((char*)KV + j*(KSTR*2) + gg*16) = kv;
    }
  }
  __syncthreads();

  if (w < 2) {
    const int rb = w * 16;
    const int mrow = l & 15, q4 = l >> 4;
    const short8 aq0 = *(const short8*)((const char*)Qs + (rb + mrow)*(KSTR*2) + q4*16);
    const short8 aq1 = *(const short8*)((const char*)Qs + (rb + mrow)*(KSTR*2) + 64 + q4*16);
    f32x4 cacc[NKT];
    #pragma unroll
    for (int ct = 0; ct < NKT; ++ct) {
      f32x4 c; c[0]=0.f; c[1]=0.f; c[2]=0.f; c[3]=0.f;
      const short8 b0 = *(const short8*)((const char*)KV + (ct*16 + mrow)*(KSTR*2) + q4*16);
      const short8 b1 = *(const short8*)((const char*)KV + (ct*16 + mrow)*(KSTR*2) + 64 + q4*16);
      c = __builtin_amdgcn_mfma_f32_16x16x32_bf16(aq0, b0, c, 0, 0, 0);
      c = __builtin_amdgcn_mfma_f32_16x16x32_bf16(aq1, b1, c, 0, 0, 0);
      cacc[ct] = c;
    }
    #pragma unroll
    for (int r = 0; r < 4; ++r) {
      const int iq = q0 + rb + q4*4 + r;
      float m = -1e30f;
      #pragma unroll
      for (int ct = 0; ct < NKT; ++ct) {
        const int jj = ct*16 + mrow;
        const int j = k0 + jj;
        const bool ok = (jj < nk) && (j >= iq - WIN) && (j <= iq + WIN);
        const float s = ok ? cacc[ct][r] * 0.125f : -1e30f;
        cacc[ct][r] = s;
        m = fmaxf(m, s);
      }
      m = fmaxf(m, __shfl_xor(m, 1, 64));
      m = fmaxf(m, __shfl_xor(m, 2, 64));
      m = fmaxf(m, __shfl_xor(m, 4, 64));
      m = fmaxf(m, __shfl_xor(m, 8, 64));
      float s = 0.f;
      #pragma unroll
      for (int ct = 0; ct < NKT; ++ct) {
        const float e = __expf(cacc[ct][r] - m);
        cacc[ct][r] = e;
        s += e;
      }
      s += __shfl_xor(s, 1, 64);
      s += __shfl_xor(s, 2, 64);
      s += __shfl_xor(s, 4, 64);
      s += __shfl_xor(s, 8, 64);
      const float rinv = 1.0f / s;
      #pragma unroll
      for (int ct = 0; ct < NKT; ++ct)
        Ps[(rb + q4*4 + r) * PSTR + ct*16 + mrow] = f2bf(cacc[ct][r] * rinv);
    }
  }
  __syncthreads();

  {
    uint16_t* Vt = KV;
    const int gg = t & 7;
    for (int j = t >> 3; j < NKP; j += 32) {
      if (j < nk) {
        const uint4 v = *(const uint4*)(qkv + (size_t)(b*SEQ + k0 + j) * 3072 + 2048 + hh*64 + gg*8);
        uint16_t e[8] = { (uint16_t)(v.x & 0xffff), (uint16_t)(v.x >> 16),
                          (uint16_t)(v.y & 0xffff), (uint16_t)(v.y >> 16),
                          (uint16_t)(v.z & 0xffff), (uint16_t)(v.z >> 16),
                          (uint16_t)(v.w & 0xffff), (uint16_t)(v.w >> 16) };
        #pragma unroll
        for (int dd = 0; dd < 8; ++dd) Vt[(gg*8 + dd) * PSTR + j] = e[dd];
      } else {
        #pragma unroll
        for (int dd = 0; dd < 8; ++dd) Vt[(gg*8 + dd) * PSTR + j] = 0;
      }
    }
  }
  __syncthreads();

  {
    const uint16_t* Vt = KV;
    const int mrow = l & 15, q4 = l >> 4;
    const int rt = w & 1, dt0 = (w >> 1) * 2;
    f32x4 o0, o1;
    #pragma unroll
    for (int e = 0; e < 4; ++e) { o0[e] = 0.f; o1[e] = 0.f; }
    #pragma unroll
    for (int ks = 0; ks < 9; ++ks) {
      const short8 a  = *(const short8*)((const char*)Ps + (rt*16 + mrow)*(PSTR*2) + ks*64 + q4*16);
      const short8 v0 = *(const short8*)((const char*)Vt + ((dt0  )*16 + mrow)*(PSTR*2) + ks*64 + q4*16);
      const short8 v1 = *(const short8*)((const char*)Vt + ((dt0+1)*16 + mrow)*(PSTR*2) + ks*64 + q4*16);
      o0 = __builtin_amdgcn_mfma_f32_16x16x32_bf16(a, v0, o0, 0, 0, 0);
      o1 = __builtin_amdgcn_mfma_f32_16x16x32_bf16(a, v1, o1, 0, 0, 0);
    }
    #pragma unroll
    for (int r = 0; r < 4; ++r) {
      const int iq = q0 + rt*16 + q4*4 + r;
      const size_t rowoff = (size_t)(b*SEQ + iq) * DMODEL + hh*64;
      out[rowoff + (dt0  )*16 + mrow] = f2bf(o0[r]);
      out[rowoff + (dt0+1)*16 + mrow] = f2bf(o1[r]);
    }
  }
}

// --------------------------------- launch ----------------------------------
extern "C" void kernel_launch(void* const* d_in, const int* in_sizes, int n_in,
                              void* d_out, int out_size, void* d_ws, size_t ws_size,
                              hipStream_t stream)
{
  const float* x    = (const float*)d_in[0];
  const float* ln1g = (const float*)d_in[1];
  const float* ln1b = (const float*)d_in[2];
  const float* wqkv = (const float*)d_in[3];
  const float* wout = (const float*)d_in[4];
  const float* bout = (const float*)d_in[5];
  const float* ln2g = (const float*)d_in[6];
  const float* ln2b = (const float*)d_in[7];
  const float* wff1 = (const float*)d_in[8];
  const float* bff1 = (const float*)d_in[9];
  const float* wff2 = (const float*)d_in[10];
  const float* bff2 = (const float*)d_in[11];
  float* out = (float*)d_out;

  char* ws = (char*)d_ws;
  const size_t MB = (size_t)1 << 20;
  uint16_t* Wqkv = (uint16_t*)(ws);            //  0-6
  uint16_t* Wout = (uint16_t*)(ws +  6*MB);    //  6-8
  uint16_t* Wff1 = (uint16_t*)(ws +  8*MB);    //  8-16
  uint16_t* Wff2 = (uint16_t*)(ws + 16*MB);    // 16-24
  uint16_t* QKV  = (uint16_t*)(ws + 24*MB);    // 24-48 (dead after attn)
  uint16_t* H1   = (uint16_t*)(ws + 48*MB);    // 48-56 h1 -> attn_out
  uint16_t* AT   = H1;
  float*    X2f  = (float*)   (ws + 56*MB);    // 56-72 fp32 (live to end)
  uint16_t* H2   = (uint16_t*)(ws + 72*MB);    // 72-80
  uint16_t* FF1  = (uint16_t*)(ws + 24*MB);    // 24-56 (qkv+attn dead)
  // high-water: 80 MB (ws proven >= 97 MB by round-3 diagnostic)

  // 1) weights fp32->bf16 + h1 = LN1(x)   (fused, 16384 blocks)
  cvtln_kernel<<<16384, 256, 0, stream>>>(wqkv, wout, wff1, wff2,
                                          Wqkv, Wout, Wff1, Wff2,
                                          x, ln1g, ln1b, H1);
  // 2) qkv = h1 @ w_qkv^T                 (1536 blocks, 6/CU)
  gemm_qkv<<<dim3(3072/64, MTOK/128), 256, 0, stream>>>(H1, Wqkv, QKV, MTOK, 3072, DMODEL);
  // 3) attn_out = local_attention(qkv)
  attn_kernel<<<dim3(SEQ/TQ, NHEAD, NB), 256, 0, stream>>>(QKV, AT);
  // 4) x2 = attn_out @ w_out^T + b_out + x  (1024 blocks, 4/CU, fp32)
  gemm64<<<dim3(DMODEL/64, MTOK/64), 256, 0, stream>>>(AT, Wout, bout, x, X2f, MTOK, DMODEL, DMODEL);
  // 5) h2 = LN2(x2)
  ln_kernel<<<MTOK, 256, 0, stream>>>(X2f, ln2g, ln2b, H2);
  // 6) ff1 = gelu(h2 @ w_ff1^T + b_ff1)   (1024 blocks, 4/CU)
  gemm_bt<2><<<dim3(FFDIM/128, MTOK/128), 256, 0, stream>>>(H2, Wff1, bff1, FF1, MTOK, FFDIM, DMODEL);
  // 7) out = ff1 @ w_ff2^T + b_ff2 + x2   (1024 blocks, 4/CU, K=4096, fp32)
  gemm64<<<dim3(DMODEL/64, MTOK/64), 256, 0, stream>>>(FF1, Wff2, bff2, X2f, out, MTOK, DMODEL, FFDIM);
}